// Round 1
// 1245.515 us; speedup vs baseline: 1.0187x; 1.0187x over previous
//
#include <hip/hip_runtime.h>
#include <math.h>

// Problem constants
#define Bb 16
#define Cc 512
#define Nn 4096
#define CN (512L * 4096)           // elements of one [C][N] or [N][C] plane

typedef __bf16 bf16x8 __attribute__((ext_vector_type(8)));
typedef float  floatx4 __attribute__((ext_vector_type(4)));

__device__ __forceinline__ unsigned short f2bf(float f) {
    unsigned int u = __float_as_uint(f);
    unsigned int r = (u + 0x7FFFu + ((u >> 16) & 1u)) >> 16;
    return (unsigned short)r;
}
__device__ __forceinline__ float bf2f(unsigned short s) {
    return __uint_as_float(((unsigned int)s) << 16);
}

// async 16B global->LDS (dest = wave-uniform base + lane*16)
__device__ __forceinline__ void gload16(const void* g, void* l) {
    __builtin_amdgcn_global_load_lds(
        (const __attribute__((address_space(1))) unsigned int*)g,
        (__attribute__((address_space(3))) unsigned int*)l,
        16, 0, 0);
}

// ---------------------------------------------------------------------------
// NT bf16 MFMA GEMM: C[M x N] = scale * (A[M x K] @ B[N x K]^T) + bias[col]
// A rows K-contiguous (pitch lda), B rows K-contiguous (pitch ldb).
// 128x128 tile, BK=32, 256 threads = 4 waves (2x2 of 64x64).
// LDS layout == fragment order: subtile s (16 rows), slot lane*16B holds
// A[s*16 + (lane&15)][(lane>>4)*8 .. +7]  -> ds_read_b128 conflict-free.
//
// Pipelined (T3/T4/T5): double-buffered LDS, next K-tile's global_load_lds
// issued BEFORE computing current tile, counted s_waitcnt vmcnt(4) (each
// thread's 4 next-tile loads stay in flight across the barrier), raw
// s_barrier (avoids compiler's vmcnt(0) drain at __syncthreads), setprio
// around the MFMA cluster.
// OUTF32: write float, else bf16. SPLIT: A switches source at k=asplit.
// ---------------------------------------------------------------------------
template<int OUTF32, int SPLIT>
__global__ __launch_bounds__(256) void gemm_bt(
    const unsigned short* __restrict__ A1,
    const unsigned short* __restrict__ A2, int lda, int asplit,
    const unsigned short* __restrict__ B, int ldb,
    const float* __restrict__ bias,
    void* __restrict__ Cv, int ldc,
    int K, float scale,
    long sA, long sB, long sC)
{
    __shared__ __align__(16) unsigned short Alds[2][8 * 512];
    __shared__ __align__(16) unsigned short Blds[2][8 * 512];

    const int t    = threadIdx.x;
    const int lane = t & 63;
    const int wave = t >> 6;
    const int m0 = blockIdx.y * 128;
    const int n0 = blockIdx.x * 128;
    const int wm = (wave >> 1) * 64;
    const int wn = (wave & 1) * 64;

    const unsigned short* Ab1 = A1 + (size_t)blockIdx.z * sA;
    const unsigned short* Ab2 = SPLIT ? (A2 + (size_t)blockIdx.z * sA) : nullptr;
    const unsigned short* Bb_ = B + (size_t)blockIdx.z * sB;

    const int srow = lane & 15;         // row within 16-row subtile
    const int sk   = (lane >> 4) * 8;   // k-offset of this lane's 8 elems
    const int sub0 = wave * 2;          // this wave stages subtiles sub0, sub0+1

    // Per-thread staging pointers (k advances by +k0; SPLIT handled by a
    // constant pointer jump so the increment stays trivial).
    const unsigned short* gA0 = Ab1 + (size_t)(m0 + (sub0    ) * 16 + srow) * lda + sk;
    const unsigned short* gA1 = Ab1 + (size_t)(m0 + (sub0 + 1) * 16 + srow) * lda + sk;
    const unsigned short* gB0 = Bb_ + (size_t)(n0 + (sub0    ) * 16 + srow) * ldb + sk;
    const unsigned short* gB1 = Bb_ + (size_t)(n0 + (sub0 + 1) * 16 + srow) * ldb + sk;
    const ptrdiff_t sjump = SPLIT ? (Ab2 - Ab1) - (ptrdiff_t)asplit : 0;

    auto stage = [&](int buf, int k0) {
        const unsigned short* a0 = gA0 + k0;
        const unsigned short* a1 = gA1 + k0;
        if (SPLIT && k0 >= asplit) { a0 += sjump; a1 += sjump; }
        gload16(a0,       &Alds[buf][(sub0    ) * 512]);
        gload16(gB0 + k0, &Blds[buf][(sub0    ) * 512]);
        gload16(a1,       &Alds[buf][(sub0 + 1) * 512]);
        gload16(gB1 + k0, &Blds[buf][(sub0 + 1) * 512]);
    };

    floatx4 acc[4][4] = {};

    const int nt = K >> 5;
    int cur = 0;
    stage(0, 0);                         // prologue: tile 0 in flight (4 loads)

    for (int ti = 0; ti < nt; ++ti) {
        if (ti + 1 < nt) {
            stage(cur ^ 1, (ti + 1) << 5);            // +4 loads -> 8 in flight
            asm volatile("s_waitcnt vmcnt(4)" ::: "memory");   // tile ti resident
        } else {
            asm volatile("s_waitcnt vmcnt(0)" ::: "memory");   // last tile
        }
        __builtin_amdgcn_s_barrier();                 // all waves' loads landed
        __builtin_amdgcn_sched_barrier(0);            // pin: no hoist above bar

        bf16x8 af[4], bfr[4];
#pragma unroll
        for (int i = 0; i < 4; ++i) {
            af[i]  = *(const bf16x8*)&Alds[cur][((wm >> 4) + i) * 512 + lane * 8];
            bfr[i] = *(const bf16x8*)&Blds[cur][((wn >> 4) + i) * 512 + lane * 8];
        }
        __builtin_amdgcn_s_setprio(1);
#pragma unroll
        for (int i = 0; i < 4; ++i)
#pragma unroll
            for (int j = 0; j < 4; ++j)
                acc[i][j] = __builtin_amdgcn_mfma_f32_16x16x32_bf16(af[i], bfr[j], acc[i][j], 0, 0, 0);
        __builtin_amdgcn_s_setprio(0);

        asm volatile("s_waitcnt lgkmcnt(0)" ::: "memory");  // reads of buf[cur] done
        __builtin_amdgcn_s_barrier();                 // before tile ti+2 overwrites
        __builtin_amdgcn_sched_barrier(0);
        cur ^= 1;
    }

    // epilogue: C/D layout col = lane&15, row = (lane>>4)*4 + reg  [m89/m91]
    const int rbase = (lane >> 4) * 4;
    const int cofs  = lane & 15;
#pragma unroll
    for (int j = 0; j < 4; ++j) {
        int col = n0 + wn + j * 16 + cofs;
        float bv = bias ? bias[col] : 0.0f;
#pragma unroll
        for (int i = 0; i < 4; ++i) {
#pragma unroll
            for (int r = 0; r < 4; ++r) {
                int row = m0 + wm + i * 16 + rbase + r;
                float v = acc[i][j][r] * scale + bv;
                if (OUTF32) {
                    float* C = (float*)Cv + (size_t)blockIdx.z * sC;
                    C[(size_t)row * ldc + col] = v;
                } else {
                    unsigned short* C = (unsigned short*)Cv + (size_t)blockIdx.z * sC;
                    C[(size_t)row * ldc + col] = f2bf(v);
                }
            }
        }
    }
}

// ---------------------------------------------------------------------------
// fp32 -> bf16 weight cast (n multiple of 1024)
// ---------------------------------------------------------------------------
__global__ __launch_bounds__(256) void wcast(const float* __restrict__ w,
                                             unsigned short* __restrict__ o, int n)
{
    int i = (blockIdx.x * 256 + threadIdx.x) * 4;
    float4 v = *(const float4*)&w[i];
    ushort4 u;
    u.x = f2bf(v.x); u.y = f2bf(v.y); u.z = f2bf(v.z); u.w = f2bf(v.w);
    *(ushort4*)&o[i] = u;
}

// ---------------------------------------------------------------------------
// x [c][n] fp32 (pitch 4096) -> x' [n][c] bf16 (pitch 512). grid (64,8,G).
// ---------------------------------------------------------------------------
__global__ __launch_bounds__(256) void transpose_x(const float* __restrict__ x,
                                                   unsigned short* __restrict__ xp)
{
    __shared__ unsigned short tile[64][65];   // tile[n_loc][c_loc]
    const float* X = x + (size_t)blockIdx.z * CN;
    unsigned short* O = xp + (size_t)blockIdx.z * CN;
    int n0 = blockIdx.x * 64, c0 = blockIdx.y * 64;
    int tq = (threadIdx.x & 15) * 4, tr = threadIdx.x >> 4;
#pragma unroll
    for (int r = 0; r < 4; ++r) {
        int cl = tr + r * 16;
        float4 v = *(const float4*)&X[(size_t)(c0 + cl) * 4096 + n0 + tq];
        tile[tq + 0][cl] = f2bf(v.x);
        tile[tq + 1][cl] = f2bf(v.y);
        tile[tq + 2][cl] = f2bf(v.z);
        tile[tq + 3][cl] = f2bf(v.w);
    }
    __syncthreads();
#pragma unroll
    for (int r = 0; r < 4; ++r) {
        int nl = tr + r * 16;
        ushort4 o;
        o.x = tile[nl][tq + 0]; o.y = tile[nl][tq + 1];
        o.z = tile[nl][tq + 2]; o.w = tile[nl][tq + 3];
        *(ushort4*)&O[(size_t)(n0 + nl) * 512 + c0 + tq] = o;
    }
}

// ---------------------------------------------------------------------------
// q/k transform + transpose:
//   T[c][n] (bf16, pitch 4096) = neg ? -relu(q'*m') : relu(k'*m')
// sources: qkv' [n][1536] col offset coff; mqk' [n][1024] col offset coff.
// grid (64, 8, G).
// ---------------------------------------------------------------------------
__global__ __launch_bounds__(256) void qk_transform(
    const unsigned short* __restrict__ qkv, const unsigned short* __restrict__ mqk,
    unsigned short* __restrict__ T, int coff, int neg)
{
    __shared__ __align__(8) unsigned short tile[64][68];  // tile[n_loc][c_loc]
    const unsigned short* S1 = qkv + (size_t)blockIdx.z * (4096L * 1536) + coff;
    const unsigned short* S2 = mqk + (size_t)blockIdx.z * (4096L * 1024) + coff;
    unsigned short* O = T + (size_t)blockIdx.z * CN;
    int n0 = blockIdx.x * 64, c0 = blockIdx.y * 64;
    int tq = (threadIdx.x & 15) * 4, tr = threadIdx.x >> 4;
#pragma unroll
    for (int r = 0; r < 4; ++r) {
        int nl = tr + r * 16;
        ushort4 a = *(const ushort4*)&S1[(size_t)(n0 + nl) * 1536 + c0 + tq];
        ushort4 m = *(const ushort4*)&S2[(size_t)(n0 + nl) * 1024 + c0 + tq];
        float f0 = fmaxf(bf2f(a.x) * bf2f(m.x), 0.0f);
        float f1 = fmaxf(bf2f(a.y) * bf2f(m.y), 0.0f);
        float f2 = fmaxf(bf2f(a.z) * bf2f(m.z), 0.0f);
        float f3 = fmaxf(bf2f(a.w) * bf2f(m.w), 0.0f);
        if (neg) { f0 = -f0; f1 = -f1; f2 = -f2; f3 = -f3; }
        ushort4 p;
        p.x = f2bf(f0); p.y = f2bf(f1); p.z = f2bf(f2); p.w = f2bf(f3);
        *(ushort4*)&tile[nl][tq] = p;
    }
    __syncthreads();
#pragma unroll
    for (int r = 0; r < 4; ++r) {
        int cl = tr + r * 16;
        ushort4 o;
        o.x = tile[tq + 0][cl]; o.y = tile[tq + 1][cl];
        o.z = tile[tq + 2][cl]; o.w = tile[tq + 3][cl];
        *(ushort4*)&O[(size_t)(c0 + cl) * 4096 + n0 + tq] = o;
    }
}

// ---------------------------------------------------------------------------
// Row softmax (len 4096) in place on bf16 rows. One block per row.
// ---------------------------------------------------------------------------
__global__ __launch_bounds__(256) void qsoftmax_bf(unsigned short* __restrict__ Q)
{
    unsigned short* p = Q + (size_t)blockIdx.x * 4096;
    const int t = threadIdx.x;
    const int lane = t & 63;
    const int wv = t >> 6;
    __shared__ float red[8];

    float vals[16];
    float mx = -1e30f;
#pragma unroll
    for (int i = 0; i < 16; ++i) {
        float v = bf2f(p[t + i * 256]);
        vals[i] = v;
        mx = fmaxf(mx, v);
    }
#pragma unroll
    for (int off = 32; off > 0; off >>= 1) mx = fmaxf(mx, __shfl_xor(mx, off));
    if (lane == 0) red[wv] = mx;
    __syncthreads();
    mx = fmaxf(fmaxf(red[0], red[1]), fmaxf(red[2], red[3]));

    float sum = 0.0f;
#pragma unroll
    for (int i = 0; i < 16; ++i) {
        vals[i] = __expf(vals[i] - mx);
        sum += vals[i];
    }
#pragma unroll
    for (int off = 32; off > 0; off >>= 1) sum += __shfl_xor(sum, off);
    if (lane == 0) red[4 + wv] = sum;
    __syncthreads();
    sum = red[4] + red[5] + red[6] + red[7];
    float inv = 1.0f / sum;
#pragma unroll
    for (int i = 0; i < 16; ++i) p[t + i * 256] = f2bf(vals[i] * inv);
}

// ---------------------------------------------------------------------------
// Row softmax (len 512) in place fp32 + bf16 copy. One block per row.
// ---------------------------------------------------------------------------
__global__ __launch_bounds__(256) void attn_softmax_dual(
    float* __restrict__ attnf, unsigned short* __restrict__ attnb)
{
    float* p = attnf + (size_t)blockIdx.x * 512;
    unsigned short* pb = attnb + (size_t)blockIdx.x * 512;
    const int t = threadIdx.x;
    const int lane = t & 63;
    const int wv = t >> 6;
    __shared__ float red[8];

    float v0 = p[t], v1 = p[t + 256];
    float mx = fmaxf(v0, v1);
#pragma unroll
    for (int off = 32; off > 0; off >>= 1) mx = fmaxf(mx, __shfl_xor(mx, off));
    if (lane == 0) red[wv] = mx;
    __syncthreads();
    mx = fmaxf(fmaxf(red[0], red[1]), fmaxf(red[2], red[3]));

    float e0 = __expf(v0 - mx);
    float e1 = __expf(v1 - mx);
    float sum = e0 + e1;
#pragma unroll
    for (int off = 32; off > 0; off >>= 1) sum += __shfl_xor(sum, off);
    if (lane == 0) red[4 + wv] = sum;
    __syncthreads();
    sum = red[4] + red[5] + red[6] + red[7];
    float inv = 1.0f / sum;
    float a0 = e0 * inv, a1 = e1 * inv;
    p[t] = a0;        p[t + 256] = a1;
    pb[t] = f2bf(a0); pb[t + 256] = f2bf(a1);
}

// ---------------------------------------------------------------------------
// final: out[c][n] fp32 = g*r + (1-g)*y from glin'/r'/y' [n][c] bf16 (pitch 512)
// with transpose via LDS. grid (64, 8, G).
// ---------------------------------------------------------------------------
__global__ __launch_bounds__(256) void final_fuse(
    const unsigned short* __restrict__ gl, const unsigned short* __restrict__ rr,
    const unsigned short* __restrict__ yy, float* __restrict__ out)
{
    __shared__ __align__(16) float tile[64][68];   // tile[n_loc][c_loc]
    size_t bo = (size_t)blockIdx.z * CN;
    const unsigned short* G_ = gl + bo;
    const unsigned short* R_ = rr + bo;
    const unsigned short* Y_ = yy + bo;
    float* O = out + bo;
    int n0 = blockIdx.x * 64, c0 = blockIdx.y * 64;
    int tq = (threadIdx.x & 15) * 4, tr = threadIdx.x >> 4;
#pragma unroll
    for (int r = 0; r < 4; ++r) {
        int nl = tr + r * 16;
        size_t base = (size_t)(n0 + nl) * 512 + c0 + tq;
        ushort4 g4 = *(const ushort4*)&G_[base];
        ushort4 r4 = *(const ushort4*)&R_[base];
        ushort4 y4 = *(const ushort4*)&Y_[base];
        float4 o;
        float g;
        g = 1.0f / (1.0f + __expf(-bf2f(g4.x))); o.x = g * bf2f(r4.x) + (1.0f - g) * bf2f(y4.x);
        g = 1.0f / (1.0f + __expf(-bf2f(g4.y))); o.y = g * bf2f(r4.y) + (1.0f - g) * bf2f(y4.y);
        g = 1.0f / (1.0f + __expf(-bf2f(g4.z))); o.z = g * bf2f(r4.z) + (1.0f - g) * bf2f(y4.z);
        g = 1.0f / (1.0f + __expf(-bf2f(g4.w))); o.w = g * bf2f(r4.w) + (1.0f - g) * bf2f(y4.w);
        *(float4*)&tile[nl][tq] = o;
    }
    __syncthreads();
#pragma unroll
    for (int r = 0; r < 4; ++r) {
        int cl = tr + r * 16;
        float4 o;
        o.x = tile[tq + 0][cl]; o.y = tile[tq + 1][cl];
        o.z = tile[tq + 2][cl]; o.w = tile[tq + 3][cl];
        *(float4*)&O[(size_t)(c0 + cl) * 4096 + n0 + tq] = o;
    }
}

// ---------------------------------------------------------------------------
// Launch. Per-batch bf16 workspace: 4096*(512+1536+1024+512+512) = 32 MiB.
// Fixed bf16 weights: 4 MiB. Adaptive group size G (pure fn of ws_size).
// ---------------------------------------------------------------------------
extern "C" void kernel_launch(void* const* d_in, const int* in_sizes, int n_in,
                              void* d_out, int out_size, void* d_ws, size_t ws_size,
                              hipStream_t stream)
{
    const float* x    = (const float*)d_in[0];
    const float* Wqkv = (const float*)d_in[1];
    const float* bqkv = (const float*)d_in[2];
    const float* Wm   = (const float*)d_in[3];
    const float* bm   = (const float*)d_in[4];
    const float* Wg   = (const float*)d_in[5];
    const float* bg   = (const float*)d_in[6];
    const float* Wr   = (const float*)d_in[7];
    const float* br   = (const float*)d_in[8];

    float* out      = (float*)d_out;
    float* attn_all = out + (size_t)Bb * CN;

    unsigned short* wq_bf = (unsigned short*)d_ws;
    unsigned short* wm_bf = wq_bf + 1536 * 512;
    unsigned short* wg_bf = wm_bf + 1024 * 512;
    unsigned short* wr_bf = wg_bf + 512 * 1024;
    unsigned short* dyn   = wr_bf + 512 * 512;
    const size_t fixed_bytes = (size_t)(1536 * 512 + 1024 * 512 + 512 * 1024 + 512 * 512) * 2;
    const size_t per_batch_bytes = (size_t)4096 * 4096 * 2;   // 32 MiB

    int G = 16;
    while (G > 1 && fixed_bytes + (size_t)G * per_batch_bytes > ws_size) G >>= 1;

    dim3 blk(256);
    const float inv_sqrt_c = 0.044194173824159216f;

    wcast<<<1536 * 512 / 1024, blk, 0, stream>>>(Wqkv, wq_bf, 1536 * 512);
    wcast<<<1024 * 512 / 1024, blk, 0, stream>>>(Wm,   wm_bf, 1024 * 512);
    wcast<<<512 * 1024 / 1024, blk, 0, stream>>>(Wg,   wg_bf, 512 * 1024);
    wcast<<<512 * 512  / 1024, blk, 0, stream>>>(Wr,   wr_bf, 512 * 512);

    for (int b0 = 0; b0 < Bb; b0 += G) {
        unsigned short* xp   = dyn;
        unsigned short* qkvp = xp   + (size_t)G * 4096 * 512;
        unsigned short* mqkp = qkvp + (size_t)G * 4096 * 1536;
        unsigned short* qp   = mqkp + (size_t)G * 4096 * 1024;
        unsigned short* kp   = qp   + (size_t)G * CN;
        unsigned short* yp   = mqkp;                         // alias (mqk dead)
        unsigned short* glp  = mqkp + (size_t)G * CN;        // alias
        unsigned short* rp   = qp;                           // alias (_q dead)
        unsigned short* abf  = kp;                           // alias (_k dead)

        const float* xg   = x + (size_t)b0 * CN;
        float* outg       = out + (size_t)b0 * CN;
        float* attng      = attn_all + (size_t)b0 * 512 * 512;

        // x' [n][c] bf16
        transpose_x<<<dim3(64, 8, G), blk, 0, stream>>>(xg, xp);

        // qkv' = x' @ Wqkv^T + bqkv
        gemm_bt<0, 0><<<dim3(12, 32, G), blk, 0, stream>>>(
            xp, nullptr, 512, 0, wq_bf, 512, bqkv, qkvp, 1536,
            512, 1.0f, 4096L * 512, 0L, 4096L * 1536);

        // mqk' = v' @ Wm^T + bm   (v' = qkv' cols [1024,1536))
        gemm_bt<0, 0><<<dim3(8, 32, G), blk, 0, stream>>>(
            qkvp + 1024, nullptr, 1536, 0, wm_bf, 512, bm, mqkp, 1024,
            512, 1.0f, 4096L * 1536, 0L, 4096L * 1024);

        // _q0[c][n] = -relu(q*mq)^T ; _k[c][n] = relu(k*mk)^T
        qk_transform<<<dim3(64, 8, G), blk, 0, stream>>>(qkvp, mqkp, qp, 0, 1);
        qk_transform<<<dim3(64, 8, G), blk, 0, stream>>>(qkvp, mqkp, kp, 512, 0);

        // _q = softmax over n
        qsoftmax_bf<<<G * 512, blk, 0, stream>>>(qp);

        // scores = (_q @ _k^T)/sqrt(C) -> fp32 attn region
        gemm_bt<1, 0><<<dim3(4, 4, G), blk, 0, stream>>>(
            qp, nullptr, 4096, 0, kp, 4096, nullptr, attng, 512,
            4096, inv_sqrt_c, CN, CN, 512L * 512);

        // attn = softmax(scores): fp32 in place + bf16 copy
        attn_softmax_dual<<<G * 512, blk, 0, stream>>>(attng, abf);

        // y' = v' @ attn^T
        gemm_bt<0, 0><<<dim3(4, 32, G), blk, 0, stream>>>(
            qkvp + 1024, nullptr, 1536, 0, abf, 512, nullptr, yp, 512,
            512, 1.0f, 4096L * 1536, 512L * 512, 4096L * 512);

        // glin' = [y'; x'] @ Wg^T + bg  (A switches at k=512)
        gemm_bt<0, 1><<<dim3(4, 32, G), blk, 0, stream>>>(
            yp, xp, 512, 512, wg_bf, 1024, bg, glp, 512,
            1024, 1.0f, 4096L * 512, 0L, 4096L * 512);

        // r' = x' @ Wr^T + br
        gemm_bt<0, 0><<<dim3(4, 32, G), blk, 0, stream>>>(
            xp, nullptr, 512, 0, wr_bf, 512, br, rp, 512,
            512, 1.0f, 4096L * 512, 0L, 4096L * 512);

        // out[c][n] = g*r + (1-g)*y (transposing)
        final_fuse<<<dim3(64, 8, G), blk, 0, stream>>>(glp, rp, yp, outg);
    }
}

// Round 2
// 1229.574 us; speedup vs baseline: 1.0319x; 1.0130x over previous
//
#include <hip/hip_runtime.h>
#include <math.h>

// Problem constants
#define Bb 16
#define Cc 512
#define Nn 4096
#define CN (512L * 4096)           // elements of one [C][N] or [N][C] plane

typedef __bf16 bf16x8 __attribute__((ext_vector_type(8)));
typedef float  floatx4 __attribute__((ext_vector_type(4)));

__device__ __forceinline__ unsigned short f2bf(float f) {
    unsigned int u = __float_as_uint(f);
    unsigned int r = (u + 0x7FFFu + ((u >> 16) & 1u)) >> 16;
    return (unsigned short)r;
}
__device__ __forceinline__ float bf2f(unsigned short s) {
    return __uint_as_float(((unsigned int)s) << 16);
}

// async 16B global->LDS (dest = wave-uniform base + lane*16)
__device__ __forceinline__ void gload16(const void* g, void* l) {
    __builtin_amdgcn_global_load_lds(
        (const __attribute__((address_space(1))) unsigned int*)g,
        (__attribute__((address_space(3))) unsigned int*)l,
        16, 0, 0);
}

// ---------------------------------------------------------------------------
// NT bf16 MFMA GEMM: C[M x N] = scale * (A[M x K] @ B[N x K]^T) + bias[col]
// A rows K-contiguous (pitch lda), B rows K-contiguous (pitch ldb).
// 128x128 tile, BK=32, 256 threads = 4 waves (2x2 of 64x64).
// LDS layout == fragment order: subtile s (16 rows), slot lane*16B holds
// A[s*16 + (lane&15)][(lane>>4)*8 .. +7]  -> ds_read_b128 conflict-free.
//
// T1: bijective XCD swizzle (m204) so consecutive logical tiles (same
// A-panel, x-fastest order) land on the same XCD's L2 -> kills the 4x
// A-panel HBM over-fetch seen at FETCH_SIZE=274MB (ideal ~66MB).
// T3/T4: 3-stage LDS ring, loads issued 2 K-tiles ahead, counted
// s_waitcnt vmcnt(8) in steady state (4/0 at the tail), raw s_barrier,
// setprio around the MFMA cluster.
// OUTF32: write float, else bf16. SPLIT: A switches source at k=asplit.
// ---------------------------------------------------------------------------
template<int OUTF32, int SPLIT>
__global__ __launch_bounds__(256) void gemm_bt(
    const unsigned short* __restrict__ A1,
    const unsigned short* __restrict__ A2, int lda, int asplit,
    const unsigned short* __restrict__ B, int ldb,
    const float* __restrict__ bias,
    void* __restrict__ Cv, int ldc,
    int K, float scale,
    long sA, long sB, long sC)
{
    __shared__ __align__(16) unsigned short Alds[3][8 * 512];   // 3 x 8 KiB
    __shared__ __align__(16) unsigned short Blds[3][8 * 512];   // 3 x 8 KiB

    // --- T1: bijective XCD-aware block swizzle (m204). HW round-robins
    // consecutive wgid across the 8 XCDs; remap so XCD k processes a
    // CONTIGUOUS chunk of the x-fastest logical order (x-neighbors share
    // the A-panel -> panel stays in one XCD's L2).
    const int nwg  = gridDim.x * gridDim.y * gridDim.z;
    const int orig = blockIdx.x + gridDim.x * (blockIdx.y + gridDim.y * blockIdx.z);
    const int q8   = nwg >> 3, r8 = nwg & 7;
    const int xcd  = orig & 7, sub_i = orig >> 3;
    const int logical = (xcd < r8 ? xcd * (q8 + 1) : r8 * (q8 + 1) + (xcd - r8) * q8) + sub_i;
    const int bx = logical % gridDim.x;
    const int btmp = logical / gridDim.x;
    const int by = btmp % gridDim.y;
    const int bz = btmp / gridDim.y;

    const int t    = threadIdx.x;
    const int lane = t & 63;
    const int wave = t >> 6;
    const int m0 = by * 128;
    const int n0 = bx * 128;
    const int wm = (wave >> 1) * 64;
    const int wn = (wave & 1) * 64;

    const unsigned short* Ab1 = A1 + (size_t)bz * sA;
    const unsigned short* Ab2 = SPLIT ? (A2 + (size_t)bz * sA) : nullptr;
    const unsigned short* Bb_ = B + (size_t)bz * sB;

    const int srow = lane & 15;         // row within 16-row subtile
    const int sk   = (lane >> 4) * 8;   // k-offset of this lane's 8 elems
    const int sub0 = wave * 2;          // this wave stages subtiles sub0, sub0+1

    const unsigned short* gA0 = Ab1 + (size_t)(m0 + (sub0    ) * 16 + srow) * lda + sk;
    const unsigned short* gA1 = Ab1 + (size_t)(m0 + (sub0 + 1) * 16 + srow) * lda + sk;
    const unsigned short* gB0 = Bb_ + (size_t)(n0 + (sub0    ) * 16 + srow) * ldb + sk;
    const unsigned short* gB1 = Bb_ + (size_t)(n0 + (sub0 + 1) * 16 + srow) * ldb + sk;
    const ptrdiff_t sjump = SPLIT ? (Ab2 - Ab1) - (ptrdiff_t)asplit : 0;

    auto stage = [&](int buf, int k0) {
        const unsigned short* a0 = gA0 + k0;
        const unsigned short* a1 = gA1 + k0;
        if (SPLIT && k0 >= asplit) { a0 += sjump; a1 += sjump; }
        gload16(a0,       &Alds[buf][(sub0    ) * 512]);
        gload16(gB0 + k0, &Blds[buf][(sub0    ) * 512]);
        gload16(a1,       &Alds[buf][(sub0 + 1) * 512]);
        gload16(gB1 + k0, &Blds[buf][(sub0 + 1) * 512]);
    };

    floatx4 acc[4][4] = {};

    const int nt = K >> 5;
    // prologue: 2 K-tiles in flight (8 loads/thread)
    stage(0, 0);
    if (nt > 1) stage(1, 32);
    int cur = 0;

    for (int ti = 0; ti < nt; ++ti) {
        if (ti + 2 < nt) {
            int bufn = cur + 2; if (bufn >= 3) bufn -= 3;   // == buf of tile ti-1 (reads done)
            stage(bufn, (ti + 2) << 5);                     // 12 in flight
            asm volatile("s_waitcnt vmcnt(8)" ::: "memory");   // tile ti resident
        } else if (ti + 1 < nt) {
            asm volatile("s_waitcnt vmcnt(4)" ::: "memory");
        } else {
            asm volatile("s_waitcnt vmcnt(0)" ::: "memory");
        }
        __builtin_amdgcn_s_barrier();                 // all waves' loads landed
        __builtin_amdgcn_sched_barrier(0);            // pin: no hoist above bar

        bf16x8 af[4], bfr[4];
#pragma unroll
        for (int i = 0; i < 4; ++i) {
            af[i]  = *(const bf16x8*)&Alds[cur][((wm >> 4) + i) * 512 + lane * 8];
            bfr[i] = *(const bf16x8*)&Blds[cur][((wn >> 4) + i) * 512 + lane * 8];
        }
        __builtin_amdgcn_s_setprio(1);
#pragma unroll
        for (int i = 0; i < 4; ++i)
#pragma unroll
            for (int j = 0; j < 4; ++j)
                acc[i][j] = __builtin_amdgcn_mfma_f32_16x16x32_bf16(af[i], bfr[j], acc[i][j], 0, 0, 0);
        __builtin_amdgcn_s_setprio(0);

        asm volatile("s_waitcnt lgkmcnt(0)" ::: "memory");  // reads of buf[cur] done
        __builtin_amdgcn_s_barrier();                 // before a later stage overwrites
        __builtin_amdgcn_sched_barrier(0);
        cur = (cur == 2) ? 0 : cur + 1;
    }

    // epilogue: C/D layout col = lane&15, row = (lane>>4)*4 + reg  [m89/m91]
    const int rbase = (lane >> 4) * 4;
    const int cofs  = lane & 15;
#pragma unroll
    for (int j = 0; j < 4; ++j) {
        int col = n0 + wn + j * 16 + cofs;
        float bv = bias ? bias[col] : 0.0f;
#pragma unroll
        for (int i = 0; i < 4; ++i) {
#pragma unroll
            for (int r = 0; r < 4; ++r) {
                int row = m0 + wm + i * 16 + rbase + r;
                float v = acc[i][j][r] * scale + bv;
                if (OUTF32) {
                    float* C = (float*)Cv + (size_t)bz * sC;
                    C[(size_t)row * ldc + col] = v;
                } else {
                    unsigned short* C = (unsigned short*)Cv + (size_t)bz * sC;
                    C[(size_t)row * ldc + col] = f2bf(v);
                }
            }
        }
    }
}

// ---------------------------------------------------------------------------
// fp32 -> bf16 weight cast (n multiple of 1024)
// ---------------------------------------------------------------------------
__global__ __launch_bounds__(256) void wcast(const float* __restrict__ w,
                                             unsigned short* __restrict__ o, int n)
{
    int i = (blockIdx.x * 256 + threadIdx.x) * 4;
    float4 v = *(const float4*)&w[i];
    ushort4 u;
    u.x = f2bf(v.x); u.y = f2bf(v.y); u.z = f2bf(v.z); u.w = f2bf(v.w);
    *(ushort4*)&o[i] = u;
}

// ---------------------------------------------------------------------------
// x [c][n] fp32 (pitch 4096) -> x' [n][c] bf16 (pitch 512). grid (64,8,G).
// ---------------------------------------------------------------------------
__global__ __launch_bounds__(256) void transpose_x(const float* __restrict__ x,
                                                   unsigned short* __restrict__ xp)
{
    __shared__ unsigned short tile[64][65];   // tile[n_loc][c_loc]
    const float* X = x + (size_t)blockIdx.z * CN;
    unsigned short* O = xp + (size_t)blockIdx.z * CN;
    int n0 = blockIdx.x * 64, c0 = blockIdx.y * 64;
    int tq = (threadIdx.x & 15) * 4, tr = threadIdx.x >> 4;
#pragma unroll
    for (int r = 0; r < 4; ++r) {
        int cl = tr + r * 16;
        float4 v = *(const float4*)&X[(size_t)(c0 + cl) * 4096 + n0 + tq];
        tile[tq + 0][cl] = f2bf(v.x);
        tile[tq + 1][cl] = f2bf(v.y);
        tile[tq + 2][cl] = f2bf(v.z);
        tile[tq + 3][cl] = f2bf(v.w);
    }
    __syncthreads();
#pragma unroll
    for (int r = 0; r < 4; ++r) {
        int nl = tr + r * 16;
        ushort4 o;
        o.x = tile[nl][tq + 0]; o.y = tile[nl][tq + 1];
        o.z = tile[nl][tq + 2]; o.w = tile[nl][tq + 3];
        *(ushort4*)&O[(size_t)(n0 + nl) * 512 + c0 + tq] = o;
    }
}

// ---------------------------------------------------------------------------
// q/k transform + transpose:
//   T[c][n] (bf16, pitch 4096) = neg ? -relu(q'*m') : relu(k'*m')
// sources: qkv' [n][1536] col offset coff; mqk' [n][1024] col offset coff.
// grid (64, 8, G).
// ---------------------------------------------------------------------------
__global__ __launch_bounds__(256) void qk_transform(
    const unsigned short* __restrict__ qkv, const unsigned short* __restrict__ mqk,
    unsigned short* __restrict__ T, int coff, int neg)
{
    __shared__ __align__(8) unsigned short tile[64][68];  // tile[n_loc][c_loc]
    const unsigned short* S1 = qkv + (size_t)blockIdx.z * (4096L * 1536) + coff;
    const unsigned short* S2 = mqk + (size_t)blockIdx.z * (4096L * 1024) + coff;
    unsigned short* O = T + (size_t)blockIdx.z * CN;
    int n0 = blockIdx.x * 64, c0 = blockIdx.y * 64;
    int tq = (threadIdx.x & 15) * 4, tr = threadIdx.x >> 4;
#pragma unroll
    for (int r = 0; r < 4; ++r) {
        int nl = tr + r * 16;
        ushort4 a = *(const ushort4*)&S1[(size_t)(n0 + nl) * 1536 + c0 + tq];
        ushort4 m = *(const ushort4*)&S2[(size_t)(n0 + nl) * 1024 + c0 + tq];
        float f0 = fmaxf(bf2f(a.x) * bf2f(m.x), 0.0f);
        float f1 = fmaxf(bf2f(a.y) * bf2f(m.y), 0.0f);
        float f2 = fmaxf(bf2f(a.z) * bf2f(m.z), 0.0f);
        float f3 = fmaxf(bf2f(a.w) * bf2f(m.w), 0.0f);
        if (neg) { f0 = -f0; f1 = -f1; f2 = -f2; f3 = -f3; }
        ushort4 p;
        p.x = f2bf(f0); p.y = f2bf(f1); p.z = f2bf(f2); p.w = f2bf(f3);
        *(ushort4*)&tile[nl][tq] = p;
    }
    __syncthreads();
#pragma unroll
    for (int r = 0; r < 4; ++r) {
        int cl = tr + r * 16;
        ushort4 o;
        o.x = tile[tq + 0][cl]; o.y = tile[tq + 1][cl];
        o.z = tile[tq + 2][cl]; o.w = tile[tq + 3][cl];
        *(ushort4*)&O[(size_t)(c0 + cl) * 4096 + n0 + tq] = o;
    }
}

// ---------------------------------------------------------------------------
// Row softmax (len 4096) in place on bf16 rows. One block per row.
// ---------------------------------------------------------------------------
__global__ __launch_bounds__(256) void qsoftmax_bf(unsigned short* __restrict__ Q)
{
    unsigned short* p = Q + (size_t)blockIdx.x * 4096;
    const int t = threadIdx.x;
    const int lane = t & 63;
    const int wv = t >> 6;
    __shared__ float red[8];

    float vals[16];
    float mx = -1e30f;
#pragma unroll
    for (int i = 0; i < 16; ++i) {
        float v = bf2f(p[t + i * 256]);
        vals[i] = v;
        mx = fmaxf(mx, v);
    }
#pragma unroll
    for (int off = 32; off > 0; off >>= 1) mx = fmaxf(mx, __shfl_xor(mx, off));
    if (lane == 0) red[wv] = mx;
    __syncthreads();
    mx = fmaxf(fmaxf(red[0], red[1]), fmaxf(red[2], red[3]));

    float sum = 0.0f;
#pragma unroll
    for (int i = 0; i < 16; ++i) {
        vals[i] = __expf(vals[i] - mx);
        sum += vals[i];
    }
#pragma unroll
    for (int off = 32; off > 0; off >>= 1) sum += __shfl_xor(sum, off);
    if (lane == 0) red[4 + wv] = sum;
    __syncthreads();
    sum = red[4] + red[5] + red[6] + red[7];
    float inv = 1.0f / sum;
#pragma unroll
    for (int i = 0; i < 16; ++i) p[t + i * 256] = f2bf(vals[i] * inv);
}

// ---------------------------------------------------------------------------
// Row softmax (len 512) in place fp32 + bf16 copy. One block per row.
// ---------------------------------------------------------------------------
__global__ __launch_bounds__(256) void attn_softmax_dual(
    float* __restrict__ attnf, unsigned short* __restrict__ attnb)
{
    float* p = attnf + (size_t)blockIdx.x * 512;
    unsigned short* pb = attnb + (size_t)blockIdx.x * 512;
    const int t = threadIdx.x;
    const int lane = t & 63;
    const int wv = t >> 6;
    __shared__ float red[8];

    float v0 = p[t], v1 = p[t + 256];
    float mx = fmaxf(v0, v1);
#pragma unroll
    for (int off = 32; off > 0; off >>= 1) mx = fmaxf(mx, __shfl_xor(mx, off));
    if (lane == 0) red[wv] = mx;
    __syncthreads();
    mx = fmaxf(fmaxf(red[0], red[1]), fmaxf(red[2], red[3]));

    float e0 = __expf(v0 - mx);
    float e1 = __expf(v1 - mx);
    float sum = e0 + e1;
#pragma unroll
    for (int off = 32; off > 0; off >>= 1) sum += __shfl_xor(sum, off);
    if (lane == 0) red[4 + wv] = sum;
    __syncthreads();
    sum = red[4] + red[5] + red[6] + red[7];
    float inv = 1.0f / sum;
    float a0 = e0 * inv, a1 = e1 * inv;
    p[t] = a0;        p[t + 256] = a1;
    pb[t] = f2bf(a0); pb[t + 256] = f2bf(a1);
}

// ---------------------------------------------------------------------------
// final: out[c][n] fp32 = g*r + (1-g)*y from glin'/r'/y' [n][c] bf16 (pitch 512)
// with transpose via LDS. grid (64, 8, G).
// ---------------------------------------------------------------------------
__global__ __launch_bounds__(256) void final_fuse(
    const unsigned short* __restrict__ gl, const unsigned short* __restrict__ rr,
    const unsigned short* __restrict__ yy, float* __restrict__ out)
{
    __shared__ __align__(16) float tile[64][68];   // tile[n_loc][c_loc]
    size_t bo = (size_t)blockIdx.z * CN;
    const unsigned short* G_ = gl + bo;
    const unsigned short* R_ = rr + bo;
    const unsigned short* Y_ = yy + bo;
    float* O = out + bo;
    int n0 = blockIdx.x * 64, c0 = blockIdx.y * 64;
    int tq = (threadIdx.x & 15) * 4, tr = threadIdx.x >> 4;
#pragma unroll
    for (int r = 0; r < 4; ++r) {
        int nl = tr + r * 16;
        size_t base = (size_t)(n0 + nl) * 512 + c0 + tq;
        ushort4 g4 = *(const ushort4*)&G_[base];
        ushort4 r4 = *(const ushort4*)&R_[base];
        ushort4 y4 = *(const ushort4*)&Y_[base];
        float4 o;
        float g;
        g = 1.0f / (1.0f + __expf(-bf2f(g4.x))); o.x = g * bf2f(r4.x) + (1.0f - g) * bf2f(y4.x);
        g = 1.0f / (1.0f + __expf(-bf2f(g4.y))); o.y = g * bf2f(r4.y) + (1.0f - g) * bf2f(y4.y);
        g = 1.0f / (1.0f + __expf(-bf2f(g4.z))); o.z = g * bf2f(r4.z) + (1.0f - g) * bf2f(y4.z);
        g = 1.0f / (1.0f + __expf(-bf2f(g4.w))); o.w = g * bf2f(r4.w) + (1.0f - g) * bf2f(y4.w);
        *(float4*)&tile[nl][tq] = o;
    }
    __syncthreads();
#pragma unroll
    for (int r = 0; r < 4; ++r) {
        int cl = tr + r * 16;
        float4 o;
        o.x = tile[tq + 0][cl]; o.y = tile[tq + 1][cl];
        o.z = tile[tq + 2][cl]; o.w = tile[tq + 3][cl];
        *(float4*)&O[(size_t)(c0 + cl) * 4096 + n0 + tq] = o;
    }
}

// ---------------------------------------------------------------------------
// Launch. Per-batch bf16 workspace: 4096*(512+1536+1024+512+512) = 32 MiB.
// Fixed bf16 weights: 4 MiB. Adaptive group size G (pure fn of ws_size).
// ---------------------------------------------------------------------------
extern "C" void kernel_launch(void* const* d_in, const int* in_sizes, int n_in,
                              void* d_out, int out_size, void* d_ws, size_t ws_size,
                              hipStream_t stream)
{
    const float* x    = (const float*)d_in[0];
    const float* Wqkv = (const float*)d_in[1];
    const float* bqkv = (const float*)d_in[2];
    const float* Wm   = (const float*)d_in[3];
    const float* bm   = (const float*)d_in[4];
    const float* Wg   = (const float*)d_in[5];
    const float* bg   = (const float*)d_in[6];
    const float* Wr   = (const float*)d_in[7];
    const float* br   = (const float*)d_in[8];

    float* out      = (float*)d_out;
    float* attn_all = out + (size_t)Bb * CN;

    unsigned short* wq_bf = (unsigned short*)d_ws;
    unsigned short* wm_bf = wq_bf + 1536 * 512;
    unsigned short* wg_bf = wm_bf + 1024 * 512;
    unsigned short* wr_bf = wg_bf + 512 * 1024;
    unsigned short* dyn   = wr_bf + 512 * 512;
    const size_t fixed_bytes = (size_t)(1536 * 512 + 1024 * 512 + 512 * 1024 + 512 * 512) * 2;
    const size_t per_batch_bytes = (size_t)4096 * 4096 * 2;   // 32 MiB

    int G = 16;
    while (G > 1 && fixed_bytes + (size_t)G * per_batch_bytes > ws_size) G >>= 1;

    dim3 blk(256);
    const float inv_sqrt_c = 0.044194173824159216f;

    wcast<<<1536 * 512 / 1024, blk, 0, stream>>>(Wqkv, wq_bf, 1536 * 512);
    wcast<<<1024 * 512 / 1024, blk, 0, stream>>>(Wm,   wm_bf, 1024 * 512);
    wcast<<<512 * 1024 / 1024, blk, 0, stream>>>(Wg,   wg_bf, 512 * 1024);
    wcast<<<512 * 512  / 1024, blk, 0, stream>>>(Wr,   wr_bf, 512 * 512);

    for (int b0 = 0; b0 < Bb; b0 += G) {
        unsigned short* xp   = dyn;
        unsigned short* qkvp = xp   + (size_t)G * 4096 * 512;
        unsigned short* mqkp = qkvp + (size_t)G * 4096 * 1536;
        unsigned short* qp   = mqkp + (size_t)G * 4096 * 1024;
        unsigned short* kp   = qp   + (size_t)G * CN;
        unsigned short* yp   = mqkp;                         // alias (mqk dead)
        unsigned short* glp  = mqkp + (size_t)G * CN;        // alias
        unsigned short* rp   = qp;                           // alias (_q dead)
        unsigned short* abf  = kp;                           // alias (_k dead)

        const float* xg   = x + (size_t)b0 * CN;
        float* outg       = out + (size_t)b0 * CN;
        float* attng      = attn_all + (size_t)b0 * 512 * 512;

        // x' [n][c] bf16
        transpose_x<<<dim3(64, 8, G), blk, 0, stream>>>(xg, xp);

        // qkv' = x' @ Wqkv^T + bqkv
        gemm_bt<0, 0><<<dim3(12, 32, G), blk, 0, stream>>>(
            xp, nullptr, 512, 0, wq_bf, 512, bqkv, qkvp, 1536,
            512, 1.0f, 4096L * 512, 0L, 4096L * 1536);

        // mqk' = v' @ Wm^T + bm   (v' = qkv' cols [1024,1536))
        gemm_bt<0, 0><<<dim3(8, 32, G), blk, 0, stream>>>(
            qkvp + 1024, nullptr, 1536, 0, wm_bf, 512, bm, mqkp, 1024,
            512, 1.0f, 4096L * 1536, 0L, 4096L * 1024);

        // _q0[c][n] = -relu(q*mq)^T ; _k[c][n] = relu(k*mk)^T
        qk_transform<<<dim3(64, 8, G), blk, 0, stream>>>(qkvp, mqkp, qp, 0, 1);
        qk_transform<<<dim3(64, 8, G), blk, 0, stream>>>(qkvp, mqkp, kp, 512, 0);

        // _q = softmax over n
        qsoftmax_bf<<<G * 512, blk, 0, stream>>>(qp);

        // scores = (_q @ _k^T)/sqrt(C) -> fp32 attn region
        gemm_bt<1, 0><<<dim3(4, 4, G), blk, 0, stream>>>(
            qp, nullptr, 4096, 0, kp, 4096, nullptr, attng, 512,
            4096, inv_sqrt_c, CN, CN, 512L * 512);

        // attn = softmax(scores): fp32 in place + bf16 copy
        attn_softmax_dual<<<G * 512, blk, 0, stream>>>(attng, abf);

        // y' = v' @ attn^T
        gemm_bt<0, 0><<<dim3(4, 32, G), blk, 0, stream>>>(
            qkvp + 1024, nullptr, 1536, 0, abf, 512, nullptr, yp, 512,
            512, 1.0f, 4096L * 1536, 512L * 512, 4096L * 512);

        // glin' = [y'; x'] @ Wg^T + bg  (A switches at k=512)
        gemm_bt<0, 1><<<dim3(4, 32, G), blk, 0, stream>>>(
            yp, xp, 512, 512, wg_bf, 1024, bg, glp, 512,
            1024, 1.0f, 4096L * 512, 0L, 4096L * 512);

        // r' = x' @ Wr^T + br
        gemm_bt<0, 0><<<dim3(4, 32, G), blk, 0, stream>>>(
            xp, nullptr, 512, 0, wr_bf, 512, br, rp, 512,
            512, 1.0f, 4096L * 512, 0L, 4096L * 512);

        // out[c][n] = g*r + (1-g)*y (transposing)
        final_fuse<<<dim3(64, 8, G), blk, 0, stream>>>(glp, rp, yp, outg);
    }
}

// Round 4
// 1202.344 us; speedup vs baseline: 1.0553x; 1.0226x over previous
//
#include <hip/hip_runtime.h>
#include <math.h>

// Problem constants
#define Bb 16
#define Cc 512
#define Nn 4096
#define CN (512L * 4096)           // elements of one [C][N] or [N][C] plane

typedef __bf16 bf16x8 __attribute__((ext_vector_type(8)));
typedef float  floatx4 __attribute__((ext_vector_type(4)));

__device__ __forceinline__ unsigned short f2bf(float f) {
    unsigned int u = __float_as_uint(f);
    unsigned int r = (u + 0x7FFFu + ((u >> 16) & 1u)) >> 16;
    return (unsigned short)r;
}
__device__ __forceinline__ float bf2f(unsigned short s) {
    return __uint_as_float(((unsigned int)s) << 16);
}

// async 16B global->LDS (dest = wave-uniform base + lane*16)
__device__ __forceinline__ void gload16(const void* g, void* l) {
    __builtin_amdgcn_global_load_lds(
        (const __attribute__((address_space(1))) unsigned int*)g,
        (__attribute__((address_space(3))) unsigned int*)l,
        16, 0, 0);
}

// m204 bijective XCD swizzle: consecutive logical tiles (x-fastest, sharing
// an A-panel) land on the same XCD's private L2.
__device__ __forceinline__ void xcd_swizzle(int& bx, int& by, int& bz) {
    const int nwg  = gridDim.x * gridDim.y * gridDim.z;
    const int orig = blockIdx.x + gridDim.x * (blockIdx.y + gridDim.y * blockIdx.z);
    const int q8   = nwg >> 3, r8 = nwg & 7;
    const int xcd  = orig & 7, sub_i = orig >> 3;
    const int logical = (xcd < r8 ? xcd * (q8 + 1) : r8 * (q8 + 1) + (xcd - r8) * q8) + sub_i;
    bx = logical % gridDim.x;
    const int btmp = logical / gridDim.x;
    by = btmp % gridDim.y;
    bz = btmp / gridDim.y;
}

// ---------------------------------------------------------------------------
// 256x256-tile NT bf16 MFMA GEMM: C = scale*(A @ B^T) + bias[col].
// BK=64, 512 threads = 8 waves (2M x 4N), per-wave output 128x64.
// LDS 128 KiB: 2 buffers x (A 32 KiB + B 32 KiB). Fragment-order layout:
// subtile si = rowsub*2 + khalf (1 KiB), slot lane*16B holds
// X[rowsub*16 + (lane&15)][khalf*32 + (lane>>4)*8 .. +7] -> conflict-free
// ds_read_b128 (2-way only). Counted vmcnt(8): next tile's 8 loads stay in
// flight across a full compute phase (~1000 cy); never drained in-loop.
// OUTF32: write float, else bf16. SPLIT: A switches source at k=asplit
// (asplit % 64 == 0; both sources same pitch lda).
// ---------------------------------------------------------------------------
template<int OUTF32, int SPLIT>
__global__ __launch_bounds__(512) void gemm_bt256(
    const unsigned short* __restrict__ A1,
    const unsigned short* __restrict__ A2, int lda, int asplit,
    const unsigned short* __restrict__ B, int ldb,
    const float* __restrict__ bias,
    void* __restrict__ Cv, int ldc,
    int K, float scale,
    long sA, long sB, long sC)
{
    __shared__ __align__(16) unsigned short Alds[2][32 * 512];   // 2 x 32 KiB
    __shared__ __align__(16) unsigned short Blds[2][32 * 512];   // 2 x 32 KiB

    int bx, by, bz;
    xcd_swizzle(bx, by, bz);

    const int t    = threadIdx.x;
    const int lane = t & 63;
    const int wave = t >> 6;              // 0..7
    const int m0 = by * 256;
    const int n0 = bx * 256;
    const int wm = (wave >> 2) * 128;     // 2 M-groups of 128 rows
    const int wn = (wave & 3) * 64;       // 4 N-groups of 64 cols

    const unsigned short* Ab1 = A1 + (size_t)bz * sA;
    const unsigned short* Ab2 = SPLIT ? (A2 + (size_t)bz * sA) : nullptr;
    const unsigned short* Bb_ = B + (size_t)bz * sB;

    const int srow = lane & 15;
    const int sk8  = (lane >> 4) * 8;
    const ptrdiff_t sjump = SPLIT ? (Ab2 - Ab1) - (ptrdiff_t)asplit : 0;

    // Wave stages A subtiles wave*4..+3 and B subtiles wave*4..+3.
    // subtile si: rowsub = si>>1, khalf = si&1.
    const unsigned short* gA[4];
    const unsigned short* gB[4];
#pragma unroll
    for (int u = 0; u < 4; ++u) {
        int si = wave * 4 + u;
        int rowsub = si >> 1, kh = si & 1;
        gA[u] = Ab1 + (size_t)(m0 + rowsub * 16 + srow) * lda + kh * 32 + sk8;
        gB[u] = Bb_ + (size_t)(n0 + rowsub * 16 + srow) * ldb + kh * 32 + sk8;
    }

    auto stage = [&](int buf, int k0) {
        const bool hi = SPLIT && (k0 >= asplit);
#pragma unroll
        for (int u = 0; u < 4; ++u) {
            int si = wave * 4 + u;
            const unsigned short* a = gA[u] + k0;
            if (hi) a += sjump;
            gload16(a,          &Alds[buf][si * 512]);
            gload16(gB[u] + k0, &Blds[buf][si * 512]);
        }
    };

    floatx4 acc[8][4] = {};

    const int nt = K >> 6;               // BK = 64
    stage(0, 0);                          // prologue: 8 loads in flight
    int cur = 0;

    for (int ti = 0; ti < nt; ++ti) {
        if (ti + 1 < nt) {
            stage(cur ^ 1, (ti + 1) << 6);                    // 16 in flight
            asm volatile("s_waitcnt vmcnt(8)" ::: "memory");  // tile ti landed
        } else {
            asm volatile("s_waitcnt vmcnt(0)" ::: "memory");
        }
        __builtin_amdgcn_s_barrier();
        __builtin_amdgcn_sched_barrier(0);

        const int ra = wm >> 4;          // wave's A rowsub base (0 or 8)
        const int rb = wn >> 4;          // wave's B rowsub base (0,4,8,12)
#pragma unroll
        for (int s = 0; s < 2; ++s) {    // two K=32 steps of the BK=64 tile
            bf16x8 af[8], bfr[4];
#pragma unroll
            for (int i = 0; i < 8; ++i)
                af[i] = *(const bf16x8*)&Alds[cur][((ra + i) * 2 + s) * 512 + lane * 8];
#pragma unroll
            for (int j = 0; j < 4; ++j)
                bfr[j] = *(const bf16x8*)&Blds[cur][((rb + j) * 2 + s) * 512 + lane * 8];
            __builtin_amdgcn_s_setprio(1);
#pragma unroll
            for (int i = 0; i < 8; ++i)
#pragma unroll
                for (int j = 0; j < 4; ++j)
                    acc[i][j] = __builtin_amdgcn_mfma_f32_16x16x32_bf16(af[i], bfr[j], acc[i][j], 0, 0, 0);
            __builtin_amdgcn_s_setprio(0);
        }

        asm volatile("s_waitcnt lgkmcnt(0)" ::: "memory");    // buf[cur] reads done
        __builtin_amdgcn_s_barrier();
        __builtin_amdgcn_sched_barrier(0);
        cur ^= 1;
    }

    // epilogue: C/D layout col = lane&15, row = (lane>>4)*4 + reg  [m89/m91]
    const int rbase = (lane >> 4) * 4;
    const int cofs  = lane & 15;
#pragma unroll
    for (int j = 0; j < 4; ++j) {
        int col = n0 + wn + j * 16 + cofs;
        float bv = bias ? bias[col] : 0.0f;
#pragma unroll
        for (int i = 0; i < 8; ++i) {
#pragma unroll
            for (int r = 0; r < 4; ++r) {
                int row = m0 + wm + i * 16 + rbase + r;
                float v = acc[i][j][r] * scale + bv;
                if (OUTF32) {
                    float* C = (float*)Cv + (size_t)bz * sC;
                    C[(size_t)row * ldc + col] = v;
                } else {
                    unsigned short* C = (unsigned short*)Cv + (size_t)bz * sC;
                    C[(size_t)row * ldc + col] = f2bf(v);
                }
            }
        }
    }
}

// ---------------------------------------------------------------------------
// 128x128-tile NT bf16 MFMA GEMM (verified round-2 structure) — kept for the
// scores GEMM whose 512x512 output grid is too small for 256^2 tiles.
// 3-stage LDS ring, loads 2 K-tiles ahead, counted vmcnt(8).
// ---------------------------------------------------------------------------
template<int OUTF32, int SPLIT>
__global__ __launch_bounds__(256) void gemm_bt(
    const unsigned short* __restrict__ A1,
    const unsigned short* __restrict__ A2, int lda, int asplit,
    const unsigned short* __restrict__ B, int ldb,
    const float* __restrict__ bias,
    void* __restrict__ Cv, int ldc,
    int K, float scale,
    long sA, long sB, long sC)
{
    __shared__ __align__(16) unsigned short Alds[3][8 * 512];   // 3 x 8 KiB
    __shared__ __align__(16) unsigned short Blds[3][8 * 512];   // 3 x 8 KiB

    int bx, by, bz;
    xcd_swizzle(bx, by, bz);

    const int t    = threadIdx.x;
    const int lane = t & 63;
    const int wave = t >> 6;
    const int m0 = by * 128;
    const int n0 = bx * 128;
    const int wm = (wave >> 1) * 64;
    const int wn = (wave & 1) * 64;

    const unsigned short* Ab1 = A1 + (size_t)bz * sA;
    const unsigned short* Ab2 = SPLIT ? (A2 + (size_t)bz * sA) : nullptr;
    const unsigned short* Bb_ = B + (size_t)bz * sB;

    const int srow = lane & 15;
    const int sk   = (lane >> 4) * 8;
    const int sub0 = wave * 2;

    const unsigned short* gA0 = Ab1 + (size_t)(m0 + (sub0    ) * 16 + srow) * lda + sk;
    const unsigned short* gA1 = Ab1 + (size_t)(m0 + (sub0 + 1) * 16 + srow) * lda + sk;
    const unsigned short* gB0 = Bb_ + (size_t)(n0 + (sub0    ) * 16 + srow) * ldb + sk;
    const unsigned short* gB1 = Bb_ + (size_t)(n0 + (sub0 + 1) * 16 + srow) * ldb + sk;
    const ptrdiff_t sjump = SPLIT ? (Ab2 - Ab1) - (ptrdiff_t)asplit : 0;

    auto stage = [&](int buf, int k0) {
        const unsigned short* a0 = gA0 + k0;
        const unsigned short* a1 = gA1 + k0;
        if (SPLIT && k0 >= asplit) { a0 += sjump; a1 += sjump; }
        gload16(a0,       &Alds[buf][(sub0    ) * 512]);
        gload16(gB0 + k0, &Blds[buf][(sub0    ) * 512]);
        gload16(a1,       &Alds[buf][(sub0 + 1) * 512]);
        gload16(gB1 + k0, &Blds[buf][(sub0 + 1) * 512]);
    };

    floatx4 acc[4][4] = {};

    const int nt = K >> 5;
    stage(0, 0);
    if (nt > 1) stage(1, 32);
    int cur = 0;

    for (int ti = 0; ti < nt; ++ti) {
        if (ti + 2 < nt) {
            int bufn = cur + 2; if (bufn >= 3) bufn -= 3;
            stage(bufn, (ti + 2) << 5);
            asm volatile("s_waitcnt vmcnt(8)" ::: "memory");
        } else if (ti + 1 < nt) {
            asm volatile("s_waitcnt vmcnt(4)" ::: "memory");
        } else {
            asm volatile("s_waitcnt vmcnt(0)" ::: "memory");
        }
        __builtin_amdgcn_s_barrier();
        __builtin_amdgcn_sched_barrier(0);

        bf16x8 af[4], bfr[4];
#pragma unroll
        for (int i = 0; i < 4; ++i) {
            af[i]  = *(const bf16x8*)&Alds[cur][((wm >> 4) + i) * 512 + lane * 8];
            bfr[i] = *(const bf16x8*)&Blds[cur][((wn >> 4) + i) * 512 + lane * 8];
        }
        __builtin_amdgcn_s_setprio(1);
#pragma unroll
        for (int i = 0; i < 4; ++i)
#pragma unroll
            for (int j = 0; j < 4; ++j)
                acc[i][j] = __builtin_amdgcn_mfma_f32_16x16x32_bf16(af[i], bfr[j], acc[i][j], 0, 0, 0);
        __builtin_amdgcn_s_setprio(0);

        asm volatile("s_waitcnt lgkmcnt(0)" ::: "memory");
        __builtin_amdgcn_s_barrier();
        __builtin_amdgcn_sched_barrier(0);
        cur = (cur == 2) ? 0 : cur + 1;
    }

    const int rbase = (lane >> 4) * 4;
    const int cofs  = lane & 15;
#pragma unroll
    for (int j = 0; j < 4; ++j) {
        int col = n0 + wn + j * 16 + cofs;
        float bv = bias ? bias[col] : 0.0f;
#pragma unroll
        for (int i = 0; i < 4; ++i) {
#pragma unroll
            for (int r = 0; r < 4; ++r) {
                int row = m0 + wm + i * 16 + rbase + r;
                float v = acc[i][j][r] * scale + bv;
                if (OUTF32) {
                    float* C = (float*)Cv + (size_t)bz * sC;
                    C[(size_t)row * ldc + col] = v;
                } else {
                    unsigned short* C = (unsigned short*)Cv + (size_t)bz * sC;
                    C[(size_t)row * ldc + col] = f2bf(v);
                }
            }
        }
    }
}

// ---------------------------------------------------------------------------
// fp32 -> bf16 weight cast (n multiple of 1024)
// ---------------------------------------------------------------------------
__global__ __launch_bounds__(256) void wcast(const float* __restrict__ w,
                                             unsigned short* __restrict__ o, int n)
{
    int i = (blockIdx.x * 256 + threadIdx.x) * 4;
    float4 v = *(const float4*)&w[i];
    ushort4 u;
    u.x = f2bf(v.x); u.y = f2bf(v.y); u.z = f2bf(v.z); u.w = f2bf(v.w);
    *(ushort4*)&o[i] = u;
}

// ---------------------------------------------------------------------------
// x [c][n] fp32 (pitch 4096) -> x' [n][c] bf16 (pitch 512). grid (64,8,G).
// ---------------------------------------------------------------------------
__global__ __launch_bounds__(256) void transpose_x(const float* __restrict__ x,
                                                   unsigned short* __restrict__ xp)
{
    __shared__ unsigned short tile[64][65];   // tile[n_loc][c_loc]
    const float* X = x + (size_t)blockIdx.z * CN;
    unsigned short* O = xp + (size_t)blockIdx.z * CN;
    int n0 = blockIdx.x * 64, c0 = blockIdx.y * 64;
    int tq = (threadIdx.x & 15) * 4, tr = threadIdx.x >> 4;
#pragma unroll
    for (int r = 0; r < 4; ++r) {
        int cl = tr + r * 16;
        float4 v = *(const float4*)&X[(size_t)(c0 + cl) * 4096 + n0 + tq];
        tile[tq + 0][cl] = f2bf(v.x);
        tile[tq + 1][cl] = f2bf(v.y);
        tile[tq + 2][cl] = f2bf(v.z);
        tile[tq + 3][cl] = f2bf(v.w);
    }
    __syncthreads();
#pragma unroll
    for (int r = 0; r < 4; ++r) {
        int nl = tr + r * 16;
        ushort4 o;
        o.x = tile[nl][tq + 0]; o.y = tile[nl][tq + 1];
        o.z = tile[nl][tq + 2]; o.w = tile[nl][tq + 3];
        *(ushort4*)&O[(size_t)(n0 + nl) * 512 + c0 + tq] = o;
    }
}

// ---------------------------------------------------------------------------
// q/k transform + transpose:
//   T[c][n] (bf16, pitch 4096) = neg ? -relu(q'*m') : relu(k'*m')
// sources: qkv' [n][1536] col offset coff; mqk' [n][1024] col offset coff.
// grid (64, 8, G).
// ---------------------------------------------------------------------------
__global__ __launch_bounds__(256) void qk_transform(
    const unsigned short* __restrict__ qkv, const unsigned short* __restrict__ mqk,
    unsigned short* __restrict__ T, int coff, int neg)
{
    __shared__ __align__(8) unsigned short tile[64][68];  // tile[n_loc][c_loc]
    const unsigned short* S1 = qkv + (size_t)blockIdx.z * (4096L * 1536) + coff;
    const unsigned short* S2 = mqk + (size_t)blockIdx.z * (4096L * 1024) + coff;
    unsigned short* O = T + (size_t)blockIdx.z * CN;
    int n0 = blockIdx.x * 64, c0 = blockIdx.y * 64;
    int tq = (threadIdx.x & 15) * 4, tr = threadIdx.x >> 4;
#pragma unroll
    for (int r = 0; r < 4; ++r) {
        int nl = tr + r * 16;
        ushort4 a = *(const ushort4*)&S1[(size_t)(n0 + nl) * 1536 + c0 + tq];
        ushort4 m = *(const ushort4*)&S2[(size_t)(n0 + nl) * 1024 + c0 + tq];
        float f0 = fmaxf(bf2f(a.x) * bf2f(m.x), 0.0f);
        float f1 = fmaxf(bf2f(a.y) * bf2f(m.y), 0.0f);
        float f2 = fmaxf(bf2f(a.z) * bf2f(m.z), 0.0f);
        float f3 = fmaxf(bf2f(a.w) * bf2f(m.w), 0.0f);
        if (neg) { f0 = -f0; f1 = -f1; f2 = -f2; f3 = -f3; }
        ushort4 p;
        p.x = f2bf(f0); p.y = f2bf(f1); p.z = f2bf(f2); p.w = f2bf(f3);
        *(ushort4*)&tile[nl][tq] = p;
    }
    __syncthreads();
#pragma unroll
    for (int r = 0; r < 4; ++r) {
        int cl = tr + r * 16;
        ushort4 o;
        o.x = tile[tq + 0][cl]; o.y = tile[tq + 1][cl];
        o.z = tile[tq + 2][cl]; o.w = tile[tq + 3][cl];
        *(ushort4*)&O[(size_t)(c0 + cl) * 4096 + n0 + tq] = o;
    }
}

// ---------------------------------------------------------------------------
// Row softmax (len 4096) in place on bf16 rows. One block per row.
// ---------------------------------------------------------------------------
__global__ __launch_bounds__(256) void qsoftmax_bf(unsigned short* __restrict__ Q)
{
    unsigned short* p = Q + (size_t)blockIdx.x * 4096;
    const int t = threadIdx.x;
    const int lane = t & 63;
    const int wv = t >> 6;
    __shared__ float red[8];

    float vals[16];
    float mx = -1e30f;
#pragma unroll
    for (int i = 0; i < 16; ++i) {
        float v = bf2f(p[t + i * 256]);
        vals[i] = v;
        mx = fmaxf(mx, v);
    }
#pragma unroll
    for (int off = 32; off > 0; off >>= 1) mx = fmaxf(mx, __shfl_xor(mx, off));
    if (lane == 0) red[wv] = mx;
    __syncthreads();
    mx = fmaxf(fmaxf(red[0], red[1]), fmaxf(red[2], red[3]));

    float sum = 0.0f;
#pragma unroll
    for (int i = 0; i < 16; ++i) {
        vals[i] = __expf(vals[i] - mx);
        sum += vals[i];
    }
#pragma unroll
    for (int off = 32; off > 0; off >>= 1) sum += __shfl_xor(sum, off);
    if (lane == 0) red[4 + wv] = sum;
    __syncthreads();
    sum = red[4] + red[5] + red[6] + red[7];
    float inv = 1.0f / sum;
#pragma unroll
    for (int i = 0; i < 16; ++i) p[t + i * 256] = f2bf(vals[i] * inv);
}

// ---------------------------------------------------------------------------
// Row softmax (len 512) in place fp32 + bf16 copy. One block per row.
// ---------------------------------------------------------------------------
__global__ __launch_bounds__(256) void attn_softmax_dual(
    float* __restrict__ attnf, unsigned short* __restrict__ attnb)
{
    float* p = attnf + (size_t)blockIdx.x * 512;
    unsigned short* pb = attnb + (size_t)blockIdx.x * 512;
    const int t = threadIdx.x;
    const int lane = t & 63;
    const int wv = t >> 6;
    __shared__ float red[8];

    float v0 = p[t], v1 = p[t + 256];
    float mx = fmaxf(v0, v1);
#pragma unroll
    for (int off = 32; off > 0; off >>= 1) mx = fmaxf(mx, __shfl_xor(mx, off));
    if (lane == 0) red[wv] = mx;
    __syncthreads();
    mx = fmaxf(fmaxf(red[0], red[1]), fmaxf(red[2], red[3]));

    float e0 = __expf(v0 - mx);
    float e1 = __expf(v1 - mx);
    float sum = e0 + e1;
#pragma unroll
    for (int off = 32; off > 0; off >>= 1) sum += __shfl_xor(sum, off);
    if (lane == 0) red[4 + wv] = sum;
    __syncthreads();
    sum = red[4] + red[5] + red[6] + red[7];
    float inv = 1.0f / sum;
    float a0 = e0 * inv, a1 = e1 * inv;
    p[t] = a0;        p[t + 256] = a1;
    pb[t] = f2bf(a0); pb[t + 256] = f2bf(a1);
}

// ---------------------------------------------------------------------------
// final: out[c][n] fp32 = g*r + (1-g)*y from glin'/r'/y' [n][c] bf16 (pitch 512)
// with transpose via LDS. grid (64, 8, G).
// ---------------------------------------------------------------------------
__global__ __launch_bounds__(256) void final_fuse(
    const unsigned short* __restrict__ gl, const unsigned short* __restrict__ rr,
    const unsigned short* __restrict__ yy, float* __restrict__ out)
{
    __shared__ __align__(16) float tile[64][68];   // tile[n_loc][c_loc]
    size_t bo = (size_t)blockIdx.z * CN;
    const unsigned short* G_ = gl + bo;
    const unsigned short* R_ = rr + bo;
    const unsigned short* Y_ = yy + bo;
    float* O = out + bo;
    int n0 = blockIdx.x * 64, c0 = blockIdx.y * 64;
    int tq = (threadIdx.x & 15) * 4, tr = threadIdx.x >> 4;
#pragma unroll
    for (int r = 0; r < 4; ++r) {
        int nl = tr + r * 16;
        size_t base = (size_t)(n0 + nl) * 512 + c0 + tq;
        ushort4 g4 = *(const ushort4*)&G_[base];
        ushort4 r4 = *(const ushort4*)&R_[base];
        ushort4 y4 = *(const ushort4*)&Y_[base];
        float4 o;
        float g;
        g = 1.0f / (1.0f + __expf(-bf2f(g4.x))); o.x = g * bf2f(r4.x) + (1.0f - g) * bf2f(y4.x);
        g = 1.0f / (1.0f + __expf(-bf2f(g4.y))); o.y = g * bf2f(r4.y) + (1.0f - g) * bf2f(y4.y);
        g = 1.0f / (1.0f + __expf(-bf2f(g4.z))); o.z = g * bf2f(r4.z) + (1.0f - g) * bf2f(y4.z);
        g = 1.0f / (1.0f + __expf(-bf2f(g4.w))); o.w = g * bf2f(r4.w) + (1.0f - g) * bf2f(y4.w);
        *(float4*)&tile[nl][tq] = o;
    }
    __syncthreads();
#pragma unroll
    for (int r = 0; r < 4; ++r) {
        int cl = tr + r * 16;
        float4 o;
        o.x = tile[tq + 0][cl]; o.y = tile[tq + 1][cl];
        o.z = tile[tq + 2][cl]; o.w = tile[tq + 3][cl];
        *(float4*)&O[(size_t)(c0 + cl) * 4096 + n0 + tq] = o;
    }
}

// ---------------------------------------------------------------------------
// Launch. Per-batch bf16 workspace: 4096*(512+1536+1024+512+512) = 32 MiB.
// Fixed bf16 weights: 4 MiB. Adaptive group size G (pure fn of ws_size).
// ---------------------------------------------------------------------------
extern "C" void kernel_launch(void* const* d_in, const int* in_sizes, int n_in,
                              void* d_out, int out_size, void* d_ws, size_t ws_size,
                              hipStream_t stream)
{
    const float* x    = (const float*)d_in[0];
    const float* Wqkv = (const float*)d_in[1];
    const float* bqkv = (const float*)d_in[2];
    const float* Wm   = (const float*)d_in[3];
    const float* bm   = (const float*)d_in[4];
    const float* Wg   = (const float*)d_in[5];
    const float* bg   = (const float*)d_in[6];
    const float* Wr   = (const float*)d_in[7];
    const float* br   = (const float*)d_in[8];

    float* out      = (float*)d_out;
    float* attn_all = out + (size_t)Bb * CN;

    unsigned short* wq_bf = (unsigned short*)d_ws;
    unsigned short* wm_bf = wq_bf + 1536 * 512;
    unsigned short* wg_bf = wm_bf + 1024 * 512;
    unsigned short* wr_bf = wg_bf + 512 * 1024;
    unsigned short* dyn   = wr_bf + 512 * 512;
    const size_t fixed_bytes = (size_t)(1536 * 512 + 1024 * 512 + 512 * 1024 + 512 * 512) * 2;
    const size_t per_batch_bytes = (size_t)4096 * 4096 * 2;   // 32 MiB

    int G = 16;
    while (G > 1 && fixed_bytes + (size_t)G * per_batch_bytes > ws_size) G >>= 1;

    dim3 blk(256);
    dim3 blk512(512);
    const float inv_sqrt_c = 0.044194173824159216f;

    wcast<<<1536 * 512 / 1024, blk, 0, stream>>>(Wqkv, wq_bf, 1536 * 512);
    wcast<<<1024 * 512 / 1024, blk, 0, stream>>>(Wm,   wm_bf, 1024 * 512);
    wcast<<<512 * 1024 / 1024, blk, 0, stream>>>(Wg,   wg_bf, 512 * 1024);
    wcast<<<512 * 512  / 1024, blk, 0, stream>>>(Wr,   wr_bf, 512 * 512);

    for (int b0 = 0; b0 < Bb; b0 += G) {
        unsigned short* xp   = dyn;
        unsigned short* qkvp = xp   + (size_t)G * 4096 * 512;
        unsigned short* mqkp = qkvp + (size_t)G * 4096 * 1536;
        unsigned short* qp   = mqkp + (size_t)G * 4096 * 1024;
        unsigned short* kp   = qp   + (size_t)G * CN;
        unsigned short* yp   = mqkp;                         // alias (mqk dead)
        unsigned short* glp  = mqkp + (size_t)G * CN;        // alias
        unsigned short* rp   = qp;                           // alias (_q dead)
        unsigned short* abf  = kp;                           // alias (_k dead)

        const float* xg   = x + (size_t)b0 * CN;
        float* outg       = out + (size_t)b0 * CN;
        float* attng      = attn_all + (size_t)b0 * 512 * 512;

        // x' [n][c] bf16
        transpose_x<<<dim3(64, 8, G), blk, 0, stream>>>(xg, xp);

        // qkv' = x' @ Wqkv^T + bqkv
        gemm_bt256<0, 0><<<dim3(6, 16, G), blk512, 0, stream>>>(
            xp, nullptr, 512, 0, wq_bf, 512, bqkv, qkvp, 1536,
            512, 1.0f, 4096L * 512, 0L, 4096L * 1536);

        // mqk' = v' @ Wm^T + bm   (v' = qkv' cols [1024,1536))
        gemm_bt256<0, 0><<<dim3(4, 16, G), blk512, 0, stream>>>(
            qkvp + 1024, nullptr, 1536, 0, wm_bf, 512, bm, mqkp, 1024,
            512, 1.0f, 4096L * 1536, 0L, 4096L * 1024);

        // _q0[c][n] = -relu(q*mq)^T ; _k[c][n] = relu(k*mk)^T
        qk_transform<<<dim3(64, 8, G), blk, 0, stream>>>(qkvp, mqkp, qp, 0, 1);
        qk_transform<<<dim3(64, 8, G), blk, 0, stream>>>(qkvp, mqkp, kp, 512, 0);

        // _q = softmax over n
        qsoftmax_bf<<<G * 512, blk, 0, stream>>>(qp);

        // scores = (_q @ _k^T)/sqrt(C) -> fp32 attn region (128^2 path:
        // 512x512 output => 256^2 grid would be only 4 blocks/batch)
        gemm_bt<1, 0><<<dim3(4, 4, G), blk, 0, stream>>>(
            qp, nullptr, 4096, 0, kp, 4096, nullptr, attng, 512,
            4096, inv_sqrt_c, CN, CN, 512L * 512);

        // attn = softmax(scores): fp32 in place + bf16 copy
        attn_softmax_dual<<<G * 512, blk, 0, stream>>>(attng, abf);

        // y' = v' @ attn^T
        gemm_bt256<0, 0><<<dim3(2, 16, G), blk512, 0, stream>>>(
            qkvp + 1024, nullptr, 1536, 0, abf, 512, nullptr, yp, 512,
            512, 1.0f, 4096L * 1536, 512L * 512, 4096L * 512);

        // glin' = [y'; x'] @ Wg^T + bg  (A switches at k=512)
        gemm_bt256<0, 1><<<dim3(2, 16, G), blk512, 0, stream>>>(
            yp, xp, 512, 512, wg_bf, 1024, bg, glp, 512,
            1024, 1.0f, 4096L * 512, 0L, 4096L * 512);

        // r' = x' @ Wr^T + br
        gemm_bt256<0, 0><<<dim3(2, 16, G), blk512, 0, stream>>>(
            xp, nullptr, 512, 0, wr_bf, 512, br, rp, 512,
            512, 1.0f, 4096L * 512, 0L, 4096L * 512);

        // out[c][n] = g*r + (1-g)*y (transposing)
        final_fuse<<<dim3(64, 8, G), blk, 0, stream>>>(glp, rp, yp, outg);
    }
}

// Round 5
// 1098.585 us; speedup vs baseline: 1.1550x; 1.0944x over previous
//
#include <hip/hip_runtime.h>
#include <math.h>

// Problem constants
#define Bb 16
#define Cc 512
#define Nn 4096
#define CN (512L * 4096)           // elements of one [C][N] or [N][C] plane

typedef __bf16 bf16x8 __attribute__((ext_vector_type(8)));
typedef float  floatx4 __attribute__((ext_vector_type(4)));

__device__ __forceinline__ unsigned short f2bf(float f) {
    unsigned int u = __float_as_uint(f);
    unsigned int r = (u + 0x7FFFu + ((u >> 16) & 1u)) >> 16;
    return (unsigned short)r;
}
__device__ __forceinline__ float bf2f(unsigned short s) {
    return __uint_as_float(((unsigned int)s) << 16);
}

// async 16B global->LDS (dest = wave-uniform base + lane*16)
__device__ __forceinline__ void gload16(const void* g, void* l) {
    __builtin_amdgcn_global_load_lds(
        (const __attribute__((address_space(1))) unsigned int*)g,
        (__attribute__((address_space(3))) unsigned int*)l,
        16, 0, 0);
}

// m204 bijective XCD swizzle: consecutive logical tiles (x-fastest, sharing
// an A-panel) land on the same XCD's private L2.
__device__ __forceinline__ void xcd_swizzle(int& bx, int& by, int& bz) {
    const int nwg  = gridDim.x * gridDim.y * gridDim.z;
    const int orig = blockIdx.x + gridDim.x * (blockIdx.y + gridDim.y * blockIdx.z);
    const int q8   = nwg >> 3, r8 = nwg & 7;
    const int xcd  = orig & 7, sub_i = orig >> 3;
    const int logical = (xcd < r8 ? xcd * (q8 + 1) : r8 * (q8 + 1) + (xcd - r8) * q8) + sub_i;
    bx = logical % gridDim.x;
    const int btmp = logical / gridDim.x;
    by = btmp % gridDim.y;
    bz = btmp / gridDim.y;
}

// ---------------------------------------------------------------------------
// 256x256-tile NT bf16 MFMA GEMM: C = scale*(A @ B^T) + bias[col].
// BK=64, 512 threads = 8 waves (2M x 4N), per-wave output 128x64.
// LDS 128 KiB: 2 buffers x (A 32 KiB + B 32 KiB). Fragment-order layout:
// subtile si = rowsub*2 + khalf (1 KiB), slot lane*16B holds
// X[rowsub*16 + (lane&15)][khalf*32 + (lane>>4)*8 .. +7] -> conflict-free
// ds_read_b128 (2-way only). Counted vmcnt(8): next tile's 8 loads stay in
// flight across a full compute phase; never drained in-loop.
//
// bf16 epilogue (round 5): per-wave LDS-transpose staging -> each lane
// stores 16 CONSECUTIVE cols (32 B) of one row via 2x global_store_dwordx4.
// Replaces 128 scalar 2 B stores/lane whose half-line segments caused the
// 1.8x WRITE_SIZE amplification (362 MB vs 201 ideal, round 4 PMC).
// OUTF32: write float (scalar path), else bf16. SPLIT: A switches source at
// k=asplit (asplit % 64 == 0; both sources same pitch lda).
// ---------------------------------------------------------------------------
template<int OUTF32, int SPLIT>
__global__ __launch_bounds__(512) void gemm_bt256(
    const unsigned short* __restrict__ A1,
    const unsigned short* __restrict__ A2, int lda, int asplit,
    const unsigned short* __restrict__ B, int ldb,
    const float* __restrict__ bias,
    void* __restrict__ Cv, int ldc,
    int K, float scale,
    long sA, long sB, long sC)
{
    __shared__ __align__(16) unsigned short Alds[2][32 * 512];   // 2 x 32 KiB
    __shared__ __align__(16) unsigned short Blds[2][32 * 512];   // 2 x 32 KiB

    int bx, by, bz;
    xcd_swizzle(bx, by, bz);

    const int t    = threadIdx.x;
    const int lane = t & 63;
    const int wave = t >> 6;              // 0..7
    const int m0 = by * 256;
    const int n0 = bx * 256;
    const int wm = (wave >> 2) * 128;     // 2 M-groups of 128 rows
    const int wn = (wave & 3) * 64;       // 4 N-groups of 64 cols

    const unsigned short* Ab1 = A1 + (size_t)bz * sA;
    const unsigned short* Ab2 = SPLIT ? (A2 + (size_t)bz * sA) : nullptr;
    const unsigned short* Bb_ = B + (size_t)bz * sB;

    const int srow = lane & 15;
    const int sk8  = (lane >> 4) * 8;
    const ptrdiff_t sjump = SPLIT ? (Ab2 - Ab1) - (ptrdiff_t)asplit : 0;

    // Wave stages A subtiles wave*4..+3 and B subtiles wave*4..+3.
    // subtile si: rowsub = si>>1, khalf = si&1.
    const unsigned short* gA[4];
    const unsigned short* gB[4];
#pragma unroll
    for (int u = 0; u < 4; ++u) {
        int si = wave * 4 + u;
        int rowsub = si >> 1, kh = si & 1;
        gA[u] = Ab1 + (size_t)(m0 + rowsub * 16 + srow) * lda + kh * 32 + sk8;
        gB[u] = Bb_ + (size_t)(n0 + rowsub * 16 + srow) * ldb + kh * 32 + sk8;
    }

    auto stage = [&](int buf, int k0) {
        const bool hi = SPLIT && (k0 >= asplit);
#pragma unroll
        for (int u = 0; u < 4; ++u) {
            int si = wave * 4 + u;
            const unsigned short* a = gA[u] + k0;
            if (hi) a += sjump;
            gload16(a,          &Alds[buf][si * 512]);
            gload16(gB[u] + k0, &Blds[buf][si * 512]);
        }
    };

    floatx4 acc[8][4] = {};

    const int nt = K >> 6;               // BK = 64
    stage(0, 0);                          // prologue: 8 loads in flight
    int cur = 0;

    for (int ti = 0; ti < nt; ++ti) {
        if (ti + 1 < nt) {
            stage(cur ^ 1, (ti + 1) << 6);                    // 16 in flight
            asm volatile("s_waitcnt vmcnt(8)" ::: "memory");  // tile ti landed
        } else {
            asm volatile("s_waitcnt vmcnt(0)" ::: "memory");
        }
        __builtin_amdgcn_s_barrier();
        __builtin_amdgcn_sched_barrier(0);

        const int ra = wm >> 4;          // wave's A rowsub base (0 or 8)
        const int rb = wn >> 4;          // wave's B rowsub base (0,4,8,12)
#pragma unroll
        for (int s = 0; s < 2; ++s) {    // two K=32 steps of the BK=64 tile
            bf16x8 af[8], bfr[4];
#pragma unroll
            for (int i = 0; i < 8; ++i)
                af[i] = *(const bf16x8*)&Alds[cur][((ra + i) * 2 + s) * 512 + lane * 8];
#pragma unroll
            for (int j = 0; j < 4; ++j)
                bfr[j] = *(const bf16x8*)&Blds[cur][((rb + j) * 2 + s) * 512 + lane * 8];
            __builtin_amdgcn_s_setprio(1);
#pragma unroll
            for (int i = 0; i < 8; ++i)
#pragma unroll
                for (int j = 0; j < 4; ++j)
                    acc[i][j] = __builtin_amdgcn_mfma_f32_16x16x32_bf16(af[i], bfr[j], acc[i][j], 0, 0, 0);
            __builtin_amdgcn_s_setprio(0);
        }

        asm volatile("s_waitcnt lgkmcnt(0)" ::: "memory");    // buf[cur] reads done
        __builtin_amdgcn_s_barrier();
        __builtin_amdgcn_sched_barrier(0);
        cur ^= 1;
    }

    // epilogue: C/D layout col = lane&15, row = (lane>>4)*4 + reg  [m89/m91]
    const int rbase = (lane >> 4) * 4;
    const int cofs  = lane & 15;
    if (OUTF32) {
        float* C = (float*)Cv + (size_t)bz * sC;
#pragma unroll
        for (int j = 0; j < 4; ++j) {
            int col = n0 + wn + j * 16 + cofs;
            float bv = bias ? bias[col] : 0.0f;
#pragma unroll
            for (int i = 0; i < 8; ++i)
#pragma unroll
                for (int r = 0; r < 4; ++r) {
                    int row = m0 + wm + i * 16 + rbase + r;
                    C[(size_t)row * ldc + col] = acc[i][j][r] * scale + bv;
                }
        }
    } else {
        // Per-wave LDS transpose staging (reuses Alds; safe: K-loop's final
        // lgkmcnt(0)+barrier quiesced all LDS traffic; sbuf regions are
        // per-wave disjoint; no further barrier needed).
        unsigned short* C = (unsigned short*)Cv + (size_t)bz * sC;
        float* sbuf = (float*)&Alds[0][0] + wave * (16 * 68);   // 16x68 f32/wave
        float bvj[4];
#pragma unroll
        for (int j = 0; j < 4; ++j)
            bvj[j] = bias ? bias[n0 + wn + j * 16 + cofs] : 0.0f;
        const int rrow = lane >> 2;        // 0..15 row within stripe
        const int rcg  = (lane & 3) * 16;  // 16-col group base
        unsigned short* cbase = C + (size_t)(m0 + wm + rrow) * ldc + (n0 + wn + rcg);
#pragma unroll
        for (int i = 0; i < 8; ++i) {
#pragma unroll
            for (int j = 0; j < 4; ++j)
#pragma unroll
                for (int r = 0; r < 4; ++r)
                    sbuf[(rbase + r) * 68 + j * 16 + cofs] = acc[i][j][r] * scale + bvj[j];
            // read back transposed: lane holds row rrow, cols rcg..rcg+15
            unsigned short* cp = cbase + (size_t)i * 16 * ldc;
            {
                float4 w0 = *(const float4*)&sbuf[rrow * 68 + rcg + 0];
                float4 w1 = *(const float4*)&sbuf[rrow * 68 + rcg + 4];
                uint4 o0;
                o0.x = (unsigned)f2bf(w0.x) | ((unsigned)f2bf(w0.y) << 16);
                o0.y = (unsigned)f2bf(w0.z) | ((unsigned)f2bf(w0.w) << 16);
                o0.z = (unsigned)f2bf(w1.x) | ((unsigned)f2bf(w1.y) << 16);
                o0.w = (unsigned)f2bf(w1.z) | ((unsigned)f2bf(w1.w) << 16);
                *(uint4*)cp = o0;
            }
            {
                float4 w2 = *(const float4*)&sbuf[rrow * 68 + rcg + 8];
                float4 w3 = *(const float4*)&sbuf[rrow * 68 + rcg + 12];
                uint4 o1;
                o1.x = (unsigned)f2bf(w2.x) | ((unsigned)f2bf(w2.y) << 16);
                o1.y = (unsigned)f2bf(w2.z) | ((unsigned)f2bf(w2.w) << 16);
                o1.z = (unsigned)f2bf(w3.x) | ((unsigned)f2bf(w3.y) << 16);
                o1.w = (unsigned)f2bf(w3.z) | ((unsigned)f2bf(w3.w) << 16);
                *(uint4*)(cp + 8) = o1;
            }
        }
    }
}

// ---------------------------------------------------------------------------
// 128x128-tile NT bf16 MFMA GEMM (verified round-2 structure) — kept for the
// scores GEMM whose 512x512 output grid is too small for 256^2 tiles.
// 3-stage LDS ring, loads 2 K-tiles ahead, counted vmcnt(8).
// ---------------------------------------------------------------------------
template<int OUTF32, int SPLIT>
__global__ __launch_bounds__(256) void gemm_bt(
    const unsigned short* __restrict__ A1,
    const unsigned short* __restrict__ A2, int lda, int asplit,
    const unsigned short* __restrict__ B, int ldb,
    const float* __restrict__ bias,
    void* __restrict__ Cv, int ldc,
    int K, float scale,
    long sA, long sB, long sC)
{
    __shared__ __align__(16) unsigned short Alds[3][8 * 512];   // 3 x 8 KiB
    __shared__ __align__(16) unsigned short Blds[3][8 * 512];   // 3 x 8 KiB

    int bx, by, bz;
    xcd_swizzle(bx, by, bz);

    const int t    = threadIdx.x;
    const int lane = t & 63;
    const int wave = t >> 6;
    const int m0 = by * 128;
    const int n0 = bx * 128;
    const int wm = (wave >> 1) * 64;
    const int wn = (wave & 1) * 64;

    const unsigned short* Ab1 = A1 + (size_t)bz * sA;
    const unsigned short* Ab2 = SPLIT ? (A2 + (size_t)bz * sA) : nullptr;
    const unsigned short* Bb_ = B + (size_t)bz * sB;

    const int srow = lane & 15;
    const int sk   = (lane >> 4) * 8;
    const int sub0 = wave * 2;

    const unsigned short* gA0 = Ab1 + (size_t)(m0 + (sub0    ) * 16 + srow) * lda + sk;
    const unsigned short* gA1 = Ab1 + (size_t)(m0 + (sub0 + 1) * 16 + srow) * lda + sk;
    const unsigned short* gB0 = Bb_ + (size_t)(n0 + (sub0    ) * 16 + srow) * ldb + sk;
    const unsigned short* gB1 = Bb_ + (size_t)(n0 + (sub0 + 1) * 16 + srow) * ldb + sk;
    const ptrdiff_t sjump = SPLIT ? (Ab2 - Ab1) - (ptrdiff_t)asplit : 0;

    auto stage = [&](int buf, int k0) {
        const unsigned short* a0 = gA0 + k0;
        const unsigned short* a1 = gA1 + k0;
        if (SPLIT && k0 >= asplit) { a0 += sjump; a1 += sjump; }
        gload16(a0,       &Alds[buf][(sub0    ) * 512]);
        gload16(gB0 + k0, &Blds[buf][(sub0    ) * 512]);
        gload16(a1,       &Alds[buf][(sub0 + 1) * 512]);
        gload16(gB1 + k0, &Blds[buf][(sub0 + 1) * 512]);
    };

    floatx4 acc[4][4] = {};

    const int nt = K >> 5;
    stage(0, 0);
    if (nt > 1) stage(1, 32);
    int cur = 0;

    for (int ti = 0; ti < nt; ++ti) {
        if (ti + 2 < nt) {
            int bufn = cur + 2; if (bufn >= 3) bufn -= 3;
            stage(bufn, (ti + 2) << 5);
            asm volatile("s_waitcnt vmcnt(8)" ::: "memory");
        } else if (ti + 1 < nt) {
            asm volatile("s_waitcnt vmcnt(4)" ::: "memory");
        } else {
            asm volatile("s_waitcnt vmcnt(0)" ::: "memory");
        }
        __builtin_amdgcn_s_barrier();
        __builtin_amdgcn_sched_barrier(0);

        bf16x8 af[4], bfr[4];
#pragma unroll
        for (int i = 0; i < 4; ++i) {
            af[i]  = *(const bf16x8*)&Alds[cur][((wm >> 4) + i) * 512 + lane * 8];
            bfr[i] = *(const bf16x8*)&Blds[cur][((wn >> 4) + i) * 512 + lane * 8];
        }
        __builtin_amdgcn_s_setprio(1);
#pragma unroll
        for (int i = 0; i < 4; ++i)
#pragma unroll
            for (int j = 0; j < 4; ++j)
                acc[i][j] = __builtin_amdgcn_mfma_f32_16x16x32_bf16(af[i], bfr[j], acc[i][j], 0, 0, 0);
        __builtin_amdgcn_s_setprio(0);

        asm volatile("s_waitcnt lgkmcnt(0)" ::: "memory");
        __builtin_amdgcn_s_barrier();
        __builtin_amdgcn_sched_barrier(0);
        cur = (cur == 2) ? 0 : cur + 1;
    }

    const int rbase = (lane >> 4) * 4;
    const int cofs  = lane & 15;
#pragma unroll
    for (int j = 0; j < 4; ++j) {
        int col = n0 + wn + j * 16 + cofs;
        float bv = bias ? bias[col] : 0.0f;
#pragma unroll
        for (int i = 0; i < 4; ++i) {
#pragma unroll
            for (int r = 0; r < 4; ++r) {
                int row = m0 + wm + i * 16 + rbase + r;
                float v = acc[i][j][r] * scale + bv;
                if (OUTF32) {
                    float* C = (float*)Cv + (size_t)bz * sC;
                    C[(size_t)row * ldc + col] = v;
                } else {
                    unsigned short* C = (unsigned short*)Cv + (size_t)bz * sC;
                    C[(size_t)row * ldc + col] = f2bf(v);
                }
            }
        }
    }
}

// ---------------------------------------------------------------------------
// fp32 -> bf16 weight cast (n multiple of 1024)
// ---------------------------------------------------------------------------
__global__ __launch_bounds__(256) void wcast(const float* __restrict__ w,
                                             unsigned short* __restrict__ o, int n)
{
    int i = (blockIdx.x * 256 + threadIdx.x) * 4;
    float4 v = *(const float4*)&w[i];
    ushort4 u;
    u.x = f2bf(v.x); u.y = f2bf(v.y); u.z = f2bf(v.z); u.w = f2bf(v.w);
    *(ushort4*)&o[i] = u;
}

// ---------------------------------------------------------------------------
// x [c][n] fp32 (pitch 4096) -> x' [n][c] bf16 (pitch 512). grid (64,8,G).
// ---------------------------------------------------------------------------
__global__ __launch_bounds__(256) void transpose_x(const float* __restrict__ x,
                                                   unsigned short* __restrict__ xp)
{
    __shared__ unsigned short tile[64][65];   // tile[n_loc][c_loc]
    const float* X = x + (size_t)blockIdx.z * CN;
    unsigned short* O = xp + (size_t)blockIdx.z * CN;
    int n0 = blockIdx.x * 64, c0 = blockIdx.y * 64;
    int tq = (threadIdx.x & 15) * 4, tr = threadIdx.x >> 4;
#pragma unroll
    for (int r = 0; r < 4; ++r) {
        int cl = tr + r * 16;
        float4 v = *(const float4*)&X[(size_t)(c0 + cl) * 4096 + n0 + tq];
        tile[tq + 0][cl] = f2bf(v.x);
        tile[tq + 1][cl] = f2bf(v.y);
        tile[tq + 2][cl] = f2bf(v.z);
        tile[tq + 3][cl] = f2bf(v.w);
    }
    __syncthreads();
#pragma unroll
    for (int r = 0; r < 4; ++r) {
        int nl = tr + r * 16;
        ushort4 o;
        o.x = tile[nl][tq + 0]; o.y = tile[nl][tq + 1];
        o.z = tile[nl][tq + 2]; o.w = tile[nl][tq + 3];
        *(ushort4*)&O[(size_t)(n0 + nl) * 512 + c0 + tq] = o;
    }
}

// ---------------------------------------------------------------------------
// q/k transform + transpose:
//   T[c][n] (bf16, pitch 4096) = neg ? -relu(q'*m') : relu(k'*m')
// sources: qkv' [n][1536] col offset coff; mqk' [n][1024] col offset coff.
// grid (64, 8, G).
// ---------------------------------------------------------------------------
__global__ __launch_bounds__(256) void qk_transform(
    const unsigned short* __restrict__ qkv, const unsigned short* __restrict__ mqk,
    unsigned short* __restrict__ T, int coff, int neg)
{
    __shared__ __align__(8) unsigned short tile[64][68];  // tile[n_loc][c_loc]
    const unsigned short* S1 = qkv + (size_t)blockIdx.z * (4096L * 1536) + coff;
    const unsigned short* S2 = mqk + (size_t)blockIdx.z * (4096L * 1024) + coff;
    unsigned short* O = T + (size_t)blockIdx.z * CN;
    int n0 = blockIdx.x * 64, c0 = blockIdx.y * 64;
    int tq = (threadIdx.x & 15) * 4, tr = threadIdx.x >> 4;
#pragma unroll
    for (int r = 0; r < 4; ++r) {
        int nl = tr + r * 16;
        ushort4 a = *(const ushort4*)&S1[(size_t)(n0 + nl) * 1536 + c0 + tq];
        ushort4 m = *(const ushort4*)&S2[(size_t)(n0 + nl) * 1024 + c0 + tq];
        float f0 = fmaxf(bf2f(a.x) * bf2f(m.x), 0.0f);
        float f1 = fmaxf(bf2f(a.y) * bf2f(m.y), 0.0f);
        float f2 = fmaxf(bf2f(a.z) * bf2f(m.z), 0.0f);
        float f3 = fmaxf(bf2f(a.w) * bf2f(m.w), 0.0f);
        if (neg) { f0 = -f0; f1 = -f1; f2 = -f2; f3 = -f3; }
        ushort4 p;
        p.x = f2bf(f0); p.y = f2bf(f1); p.z = f2bf(f2); p.w = f2bf(f3);
        *(ushort4*)&tile[nl][tq] = p;
    }
    __syncthreads();
#pragma unroll
    for (int r = 0; r < 4; ++r) {
        int cl = tr + r * 16;
        ushort4 o;
        o.x = tile[tq + 0][cl]; o.y = tile[tq + 1][cl];
        o.z = tile[tq + 2][cl]; o.w = tile[tq + 3][cl];
        *(ushort4*)&O[(size_t)(c0 + cl) * 4096 + n0 + tq] = o;
    }
}

// ---------------------------------------------------------------------------
// Row softmax (len 4096) in place on bf16 rows. One block per row.
// ---------------------------------------------------------------------------
__global__ __launch_bounds__(256) void qsoftmax_bf(unsigned short* __restrict__ Q)
{
    unsigned short* p = Q + (size_t)blockIdx.x * 4096;
    const int t = threadIdx.x;
    const int lane = t & 63;
    const int wv = t >> 6;
    __shared__ float red[8];

    float vals[16];
    float mx = -1e30f;
#pragma unroll
    for (int i = 0; i < 16; ++i) {
        float v = bf2f(p[t + i * 256]);
        vals[i] = v;
        mx = fmaxf(mx, v);
    }
#pragma unroll
    for (int off = 32; off > 0; off >>= 1) mx = fmaxf(mx, __shfl_xor(mx, off));
    if (lane == 0) red[wv] = mx;
    __syncthreads();
    mx = fmaxf(fmaxf(red[0], red[1]), fmaxf(red[2], red[3]));

    float sum = 0.0f;
#pragma unroll
    for (int i = 0; i < 16; ++i) {
        vals[i] = __expf(vals[i] - mx);
        sum += vals[i];
    }
#pragma unroll
    for (int off = 32; off > 0; off >>= 1) sum += __shfl_xor(sum, off);
    if (lane == 0) red[4 + wv] = sum;
    __syncthreads();
    sum = red[4] + red[5] + red[6] + red[7];
    float inv = 1.0f / sum;
#pragma unroll
    for (int i = 0; i < 16; ++i) p[t + i * 256] = f2bf(vals[i] * inv);
}

// ---------------------------------------------------------------------------
// Row softmax (len 512) in place fp32 + bf16 copy. One block per row.
// ---------------------------------------------------------------------------
__global__ __launch_bounds__(256) void attn_softmax_dual(
    float* __restrict__ attnf, unsigned short* __restrict__ attnb)
{
    float* p = attnf + (size_t)blockIdx.x * 512;
    unsigned short* pb = attnb + (size_t)blockIdx.x * 512;
    const int t = threadIdx.x;
    const int lane = t & 63;
    const int wv = t >> 6;
    __shared__ float red[8];

    float v0 = p[t], v1 = p[t + 256];
    float mx = fmaxf(v0, v1);
#pragma unroll
    for (int off = 32; off > 0; off >>= 1) mx = fmaxf(mx, __shfl_xor(mx, off));
    if (lane == 0) red[wv] = mx;
    __syncthreads();
    mx = fmaxf(fmaxf(red[0], red[1]), fmaxf(red[2], red[3]));

    float e0 = __expf(v0 - mx);
    float e1 = __expf(v1 - mx);
    float sum = e0 + e1;
#pragma unroll
    for (int off = 32; off > 0; off >>= 1) sum += __shfl_xor(sum, off);
    if (lane == 0) red[4 + wv] = sum;
    __syncthreads();
    sum = red[4] + red[5] + red[6] + red[7];
    float inv = 1.0f / sum;
    float a0 = e0 * inv, a1 = e1 * inv;
    p[t] = a0;        p[t + 256] = a1;
    pb[t] = f2bf(a0); pb[t + 256] = f2bf(a1);
}

// ---------------------------------------------------------------------------
// final: out[c][n] fp32 = g*r + (1-g)*y from glin'/r'/y' [n][c] bf16 (pitch 512)
// with transpose via LDS. grid (64, 8, G).
// ---------------------------------------------------------------------------
__global__ __launch_bounds__(256) void final_fuse(
    const unsigned short* __restrict__ gl, const unsigned short* __restrict__ rr,
    const unsigned short* __restrict__ yy, float* __restrict__ out)
{
    __shared__ __align__(16) float tile[64][68];   // tile[n_loc][c_loc]
    size_t bo = (size_t)blockIdx.z * CN;
    const unsigned short* G_ = gl + bo;
    const unsigned short* R_ = rr + bo;
    const unsigned short* Y_ = yy + bo;
    float* O = out + bo;
    int n0 = blockIdx.x * 64, c0 = blockIdx.y * 64;
    int tq = (threadIdx.x & 15) * 4, tr = threadIdx.x >> 4;
#pragma unroll
    for (int r = 0; r < 4; ++r) {
        int nl = tr + r * 16;
        size_t base = (size_t)(n0 + nl) * 512 + c0 + tq;
        ushort4 g4 = *(const ushort4*)&G_[base];
        ushort4 r4 = *(const ushort4*)&R_[base];
        ushort4 y4 = *(const ushort4*)&Y_[base];
        float4 o;
        float g;
        g = 1.0f / (1.0f + __expf(-bf2f(g4.x))); o.x = g * bf2f(r4.x) + (1.0f - g) * bf2f(y4.x);
        g = 1.0f / (1.0f + __expf(-bf2f(g4.y))); o.y = g * bf2f(r4.y) + (1.0f - g) * bf2f(y4.y);
        g = 1.0f / (1.0f + __expf(-bf2f(g4.z))); o.z = g * bf2f(r4.z) + (1.0f - g) * bf2f(y4.z);
        g = 1.0f / (1.0f + __expf(-bf2f(g4.w))); o.w = g * bf2f(r4.w) + (1.0f - g) * bf2f(y4.w);
        *(float4*)&tile[nl][tq] = o;
    }
    __syncthreads();
#pragma unroll
    for (int r = 0; r < 4; ++r) {
        int cl = tr + r * 16;
        float4 o;
        o.x = tile[tq + 0][cl]; o.y = tile[tq + 1][cl];
        o.z = tile[tq + 2][cl]; o.w = tile[tq + 3][cl];
        *(float4*)&O[(size_t)(c0 + cl) * 4096 + n0 + tq] = o;
    }
}

// ---------------------------------------------------------------------------
// Launch. Per-batch bf16 workspace: 4096*(512+1536+1024+512+512) = 32 MiB.
// Fixed bf16 weights: 4 MiB. Adaptive group size G (pure fn of ws_size).
// ---------------------------------------------------------------------------
extern "C" void kernel_launch(void* const* d_in, const int* in_sizes, int n_in,
                              void* d_out, int out_size, void* d_ws, size_t ws_size,
                              hipStream_t stream)
{
    const float* x    = (const float*)d_in[0];
    const float* Wqkv = (const float*)d_in[1];
    const float* bqkv = (const float*)d_in[2];
    const float* Wm   = (const float*)d_in[3];
    const float* bm   = (const float*)d_in[4];
    const float* Wg   = (const float*)d_in[5];
    const float* bg   = (const float*)d_in[6];
    const float* Wr   = (const float*)d_in[7];
    const float* br   = (const float*)d_in[8];

    float* out      = (float*)d_out;
    float* attn_all = out + (size_t)Bb * CN;

    unsigned short* wq_bf = (unsigned short*)d_ws;
    unsigned short* wm_bf = wq_bf + 1536 * 512;
    unsigned short* wg_bf = wm_bf + 1024 * 512;
    unsigned short* wr_bf = wg_bf + 512 * 1024;
    unsigned short* dyn   = wr_bf + 512 * 512;
    const size_t fixed_bytes = (size_t)(1536 * 512 + 1024 * 512 + 512 * 1024 + 512 * 512) * 2;
    const size_t per_batch_bytes = (size_t)4096 * 4096 * 2;   // 32 MiB

    int G = 16;
    while (G > 1 && fixed_bytes + (size_t)G * per_batch_bytes > ws_size) G >>= 1;

    dim3 blk(256);
    dim3 blk512(512);
    const float inv_sqrt_c = 0.044194173824159216f;

    wcast<<<1536 * 512 / 1024, blk, 0, stream>>>(Wqkv, wq_bf, 1536 * 512);
    wcast<<<1024 * 512 / 1024, blk, 0, stream>>>(Wm,   wm_bf, 1024 * 512);
    wcast<<<512 * 1024 / 1024, blk, 0, stream>>>(Wg,   wg_bf, 512 * 1024);
    wcast<<<512 * 512  / 1024, blk, 0, stream>>>(Wr,   wr_bf, 512 * 512);

    for (int b0 = 0; b0 < Bb; b0 += G) {
        unsigned short* xp   = dyn;
        unsigned short* qkvp = xp   + (size_t)G * 4096 * 512;
        unsigned short* mqkp = qkvp + (size_t)G * 4096 * 1536;
        unsigned short* qp   = mqkp + (size_t)G * 4096 * 1024;
        unsigned short* kp   = qp   + (size_t)G * CN;
        unsigned short* yp   = mqkp;                         // alias (mqk dead)
        unsigned short* glp  = mqkp + (size_t)G * CN;        // alias
        unsigned short* rp   = qp;                           // alias (_q dead)
        unsigned short* abf  = kp;                           // alias (_k dead)

        const float* xg   = x + (size_t)b0 * CN;
        float* outg       = out + (size_t)b0 * CN;
        float* attng      = attn_all + (size_t)b0 * 512 * 512;

        // x' [n][c] bf16
        transpose_x<<<dim3(64, 8, G), blk, 0, stream>>>(xg, xp);

        // qkv' = x' @ Wqkv^T + bqkv
        gemm_bt256<0, 0><<<dim3(6, 16, G), blk512, 0, stream>>>(
            xp, nullptr, 512, 0, wq_bf, 512, bqkv, qkvp, 1536,
            512, 1.0f, 4096L * 512, 0L, 4096L * 1536);

        // mqk' = v' @ Wm^T + bm   (v' = qkv' cols [1024,1536))
        gemm_bt256<0, 0><<<dim3(4, 16, G), blk512, 0, stream>>>(
            qkvp + 1024, nullptr, 1536, 0, wm_bf, 512, bm, mqkp, 1024,
            512, 1.0f, 4096L * 1536, 0L, 4096L * 1024);

        // _q0[c][n] = -relu(q*mq)^T ; _k[c][n] = relu(k*mk)^T
        qk_transform<<<dim3(64, 8, G), blk, 0, stream>>>(qkvp, mqkp, qp, 0, 1);
        qk_transform<<<dim3(64, 8, G), blk, 0, stream>>>(qkvp, mqkp, kp, 512, 0);

        // _q = softmax over n
        qsoftmax_bf<<<G * 512, blk, 0, stream>>>(qp);

        // scores = (_q @ _k^T)/sqrt(C) -> fp32 attn region (128^2 path:
        // 512x512 output => 256^2 grid would be only 4 blocks/batch)
        gemm_bt<1, 0><<<dim3(4, 4, G), blk, 0, stream>>>(
            qp, nullptr, 4096, 0, kp, 4096, nullptr, attng, 512,
            4096, inv_sqrt_c, CN, CN, 512L * 512);

        // attn = softmax(scores): fp32 in place + bf16 copy
        attn_softmax_dual<<<G * 512, blk, 0, stream>>>(attng, abf);

        // y' = v' @ attn^T
        gemm_bt256<0, 0><<<dim3(2, 16, G), blk512, 0, stream>>>(
            qkvp + 1024, nullptr, 1536, 0, abf, 512, nullptr, yp, 512,
            512, 1.0f, 4096L * 1536, 512L * 512, 4096L * 512);

        // glin' = [y'; x'] @ Wg^T + bg  (A switches at k=512)
        gemm_bt256<0, 1><<<dim3(2, 16, G), blk512, 0, stream>>>(
            yp, xp, 512, 512, wg_bf, 1024, bg, glp, 512,
            1024, 1.0f, 4096L * 512, 0L, 4096L * 512);

        // r' = x' @ Wr^T + br
        gemm_bt256<0, 0><<<dim3(2, 16, G), blk512, 0, stream>>>(
            xp, nullptr, 512, 0, wr_bf, 512, br, rp, 512,
            512, 1.0f, 4096L * 512, 0L, 4096L * 512);

        // out[c][n] = g*r + (1-g)*y (transposing)
        final_fuse<<<dim3(64, 8, G), blk, 0, stream>>>(glp, rp, yp, outg);
    }
}